// Round 8
// baseline (271.071 us; speedup 1.0000x reference)
//
#include <hip/hip_runtime.h>
#include <math.h>

// EngineOrderFFT via batched Bluestein, fully LDS-resident per row.
// |X| = |conv[:, :K]|. M=16384 as 128x128 four-step inside ONE workgroup.
// R7: back to R3's proven occupancy point (1024 thr, single v[8] cores,
// ~64-80 VGPR, 16 waves/CU) + structural L2 fixes:
//   - 256 blocks x 2 channels (rr loop): ALL blocks co-resident in one
//     dispatch round; ch-siblings of a batch on the same XCD (cpair*64+b)
//     so strided x-reads are fetched once and partial out-lines merge in L2.
//   - R4-proven VALU cuts: sWhi/sWlo twiddle tables + cmul chains (no
//     sincos in hot path), chirp-build quadratic recurrence, HZ/HOUT trims.

static constexpr int Bn = 64;
static constexpr int Nn = 8192;
static constexpr int Mm = 16384;

#define PI_F 3.14159265358979323846f
#define TWO_PI_F 6.28318530717958647692f
#define R2_F 0.70710678118654752f

__device__ __forceinline__ int compute_n(float rpm) {
    // ref: pad = floor((40*60/rpm - 1)*8192) in f32; n = 8192 + pad
    return 8192 + (int)floorf((2400.0f / rpm - 1.0f) * 8192.0f);
}
__device__ __forceinline__ float2 cmul(float2 a, float2 b) {
    return make_float2(a.x*b.x - a.y*b.y, a.x*b.y + a.y*b.x);
}
__device__ __forceinline__ float2 cadd(float2 a, float2 b){ return make_float2(a.x+b.x, a.y+b.y); }
__device__ __forceinline__ float2 csub(float2 a, float2 b){ return make_float2(a.x-b.x, a.y-b.y); }
__device__ __forceinline__ float2 shflx1(float2 v) {
    return make_float2(__shfl_xor(v.x, 1, 64), __shfl_xor(v.y, 1, 64));
}

#define BF(lo,hi,tw) { float2 _d = csub(lo,hi); lo = cadd(lo,hi); hi = cmul(_d, tw); }
#define BT(lo,hi,tw) { float2 _b = cmul(hi,tw); hi = csub(lo,_b); lo = cadd(lo,_b); }
#define SELC(r,c0,s0,c1,s1) ((r) ? make_float2(c1,s1) : make_float2(c0,s0))

// element (r,c) of the 128x128 tile; XOR swizzle keeps all access patterns
// (rows, cols, bitrev-pos rows/cols, linear) at the wave64-b64 floor.
__device__ __forceinline__ int bigidx(int r, int c) {
    int sw = ((r & 15) ^ ((r >> 4) << 1) ^ ((c >> 4) << 1)) & 15;
    return (r << 7) + (c ^ sw);
}
template<bool COL>
__device__ __forceinline__ int taddr(int w, int u) {
    return COL ? bigidx(u, w) : bigidx(w, u);
}

// W_M^{-m} from 2-level tables (Whi[m]=exp(-i*pi*m/64), Wlo[m]=exp(-i*pi*m/8192))
__device__ __forceinline__ float2 wtab(const float2* Whi, const float2* Wlo, int m) {
    return cmul(Whi[m >> 7], Wlo[m & 127]);
}

// ============ single cores w/ sincos (bhat builder, R3-proven) ============
template<bool COL>
__device__ __forceinline__ void dif128(float2 v[8], float2* L, int w, int p) {
    float sn, cs;
    __sincosf(PI_F * (float)p * (1.0f/64.0f), &sn, &cs);
    float2 w1 = make_float2(cs, -sn);
    float2 w2 = cmul(w1, w1);
    float2 w4 = cmul(w2, w2);
    BF(v[0],v[4], w1);
    BF(v[1],v[5], cmul(w1, make_float2(R2_F,-R2_F)));
    BF(v[2],v[6], make_float2(w1.y, -w1.x));
    BF(v[3],v[7], cmul(w1, make_float2(-R2_F,-R2_F)));
    float2 w2i = make_float2(w2.y, -w2.x);
    BF(v[0],v[2], w2);  BF(v[1],v[3], w2i);
    BF(v[4],v[6], w2);  BF(v[5],v[7], w2i);
    BF(v[0],v[1], w4);  BF(v[2],v[3], w4);
    BF(v[4],v[5], w4);  BF(v[6],v[7], w4);
    #pragma unroll
    for (int q = 0; q < 8; ++q) L[taddr<COL>(w, p + 16*q)] = v[q];
    int bb = p >> 1, r = p & 1;
    #pragma unroll
    for (int s = 0; s < 8; ++s) v[s] = L[taddr<COL>(w, 16*bb + r + 2*s)];
    BF(v[0],v[4], SELC(r, 1.f,0.f,                    0.92387953f,-0.38268343f));
    BF(v[1],v[5], SELC(r, 0.70710678f,-0.70710678f,   0.38268343f,-0.92387953f));
    BF(v[2],v[6], SELC(r, 0.f,-1.f,                  -0.38268343f,-0.92387953f));
    BF(v[3],v[7], SELC(r, -0.70710678f,-0.70710678f, -0.92387953f,-0.38268343f));
    BF(v[0],v[2], SELC(r, 1.f,0.f,  0.70710678f,-0.70710678f));
    BF(v[1],v[3], SELC(r, 0.f,-1.f, -0.70710678f,-0.70710678f));
    BF(v[4],v[6], SELC(r, 1.f,0.f,  0.70710678f,-0.70710678f));
    BF(v[5],v[7], SELC(r, 0.f,-1.f, -0.70710678f,-0.70710678f));
    #pragma unroll
    for (int s = 0; s < 8; s += 2) {
        float2 d = csub(v[s], v[s+1]);
        v[s] = cadd(v[s], v[s+1]);
        v[s+1] = r ? make_float2(d.y, -d.x) : d;
    }
    #pragma unroll
    for (int s = 0; s < 8; ++s) {
        float2 o = shflx1(v[s]);
        v[s] = r ? csub(o, v[s]) : cadd(v[s], o);
    }
}

// ============ single cores w/ table twiddles (main kernel) ============
// HZ: inputs v[4..7] are implicit zeros (not loaded).
template<bool COL, bool HZ>
__device__ __forceinline__ void difS(float2 v[8], float2* L, int w, int p,
                                     const float2* sWhi) {
    float2 w1 = sWhi[p];                        // exp(-i*pi*p/64)
    float2 w2 = cmul(w1, w1);
    float2 w4 = cmul(w2, w2);
    float2 w1b = cmul(w1, make_float2(R2_F,-R2_F));
    float2 w1c = make_float2(w1.y, -w1.x);
    float2 w1d = cmul(w1, make_float2(-R2_F,-R2_F));
    float2 w2i = make_float2(w2.y, -w2.x);
    if (HZ) {
        v[4] = cmul(v[0], w1);
        v[5] = cmul(v[1], w1b);
        v[6] = cmul(v[2], w1c);
        v[7] = cmul(v[3], w1d);
    } else {
        BF(v[0],v[4], w1);
        BF(v[1],v[5], w1b);
        BF(v[2],v[6], w1c);
        BF(v[3],v[7], w1d);
    }
    BF(v[0],v[2], w2);  BF(v[1],v[3], w2i);
    BF(v[4],v[6], w2);  BF(v[5],v[7], w2i);
    BF(v[0],v[1], w4);  BF(v[2],v[3], w4);
    BF(v[4],v[5], w4);  BF(v[6],v[7], w4);
    #pragma unroll
    for (int q = 0; q < 8; ++q) L[taddr<COL>(w, p + 16*q)] = v[q];
    int bb = p >> 1, r = p & 1;
    #pragma unroll
    for (int s = 0; s < 8; ++s) v[s] = L[taddr<COL>(w, 16*bb + r + 2*s)];
    BF(v[0],v[4], SELC(r, 1.f,0.f,                    0.92387953f,-0.38268343f));
    BF(v[1],v[5], SELC(r, 0.70710678f,-0.70710678f,   0.38268343f,-0.92387953f));
    BF(v[2],v[6], SELC(r, 0.f,-1.f,                  -0.38268343f,-0.92387953f));
    BF(v[3],v[7], SELC(r, -0.70710678f,-0.70710678f, -0.92387953f,-0.38268343f));
    BF(v[0],v[2], SELC(r, 1.f,0.f,  0.70710678f,-0.70710678f));
    BF(v[1],v[3], SELC(r, 0.f,-1.f, -0.70710678f,-0.70710678f));
    BF(v[4],v[6], SELC(r, 1.f,0.f,  0.70710678f,-0.70710678f));
    BF(v[5],v[7], SELC(r, 0.f,-1.f, -0.70710678f,-0.70710678f));
    #pragma unroll
    for (int s = 0; s < 8; s += 2) {
        float2 d = csub(v[s], v[s+1]);
        v[s] = cadd(v[s], v[s+1]);
        v[s+1] = r ? make_float2(d.y, -d.x) : d;
    }
    #pragma unroll
    for (int s = 0; s < 8; ++s) {
        float2 o = shflx1(v[s]);
        v[s] = r ? csub(o, v[s]) : cadd(v[s], o);
    }
}

// HOUT: only lo outputs v[0..3] of the final stage are produced.
template<bool COL, bool HOUT>
__device__ __forceinline__ void ditS(float2 v[8], float2* L, int w, int p,
                                     const float2* sWhi) {
    int bb = p >> 1, r = p & 1;
    #pragma unroll
    for (int s = 0; s < 8; ++s) {
        float2 o = shflx1(v[s]);
        v[s] = r ? csub(o, v[s]) : cadd(v[s], o);
    }
    #pragma unroll
    for (int s = 0; s < 8; s += 2) {
        float2 bq = v[s+1];
        if (r) bq = make_float2(-bq.y, bq.x);
        v[s+1] = csub(v[s], bq);
        v[s] = cadd(v[s], bq);
    }
    BT(v[0],v[2], SELC(r, 1.f,0.f,  0.70710678f,0.70710678f));
    BT(v[1],v[3], SELC(r, 0.f,1.f, -0.70710678f,0.70710678f));
    BT(v[4],v[6], SELC(r, 1.f,0.f,  0.70710678f,0.70710678f));
    BT(v[5],v[7], SELC(r, 0.f,1.f, -0.70710678f,0.70710678f));
    BT(v[0],v[4], SELC(r, 1.f,0.f,                   0.92387953f,0.38268343f));
    BT(v[1],v[5], SELC(r, 0.70710678f,0.70710678f,   0.38268343f,0.92387953f));
    BT(v[2],v[6], SELC(r, 0.f,1.f,                  -0.38268343f,0.92387953f));
    BT(v[3],v[7], SELC(r, -0.70710678f,0.70710678f, -0.92387953f,0.38268343f));
    #pragma unroll
    for (int s = 0; s < 8; ++s) L[taddr<COL>(w, 16*bb + r + 2*s)] = v[s];
    #pragma unroll
    for (int q = 0; q < 8; ++q) v[q] = L[taddr<COL>(w, p + 16*q)];
    float2 w1 = make_float2(sWhi[p].x, -sWhi[p].y);   // exp(+i*pi*p/64)
    float2 w2 = cmul(w1, w1);
    float2 w4 = cmul(w2, w2);
    float2 w2j = make_float2(-w2.y, w2.x);
    float2 w1b = cmul(w1, make_float2(R2_F, R2_F));
    float2 w1c = make_float2(-w1.y, w1.x);
    float2 w1d = cmul(w1, make_float2(-R2_F, R2_F));
    BT(v[0],v[1], w4); BT(v[2],v[3], w4);
    BT(v[4],v[5], w4); BT(v[6],v[7], w4);
    BT(v[0],v[2], w2);  BT(v[1],v[3], w2j);
    BT(v[4],v[6], w2);  BT(v[5],v[7], w2j);
    if (HOUT) {
        v[0] = cadd(v[0], cmul(v[4], w1));
        v[1] = cadd(v[1], cmul(v[5], w1b));
        v[2] = cadd(v[2], cmul(v[6], w1c));
        v[3] = cadd(v[3], cmul(v[7], w1d));
    } else {
        BT(v[0],v[4], w1);
        BT(v[1],v[5], w1b);
        BT(v[2],v[6], w1c);
        BT(v[3],v[7], w1d);
    }
}

// ---------------- Bhat builder: one block per b (R3-proven) ------
__global__ __launch_bounds__(1024) void eofft_bhat(const float* __restrict__ rpm,
                                                   float2* __restrict__ bhat) {
    extern __shared__ float2 L[];
    int tid = threadIdx.x;
    int f = tid >> 4, p = tid & 15;
    int b = blockIdx.x;
    int n = compute_n(rpm[b]);
    int two_n = 2 * n;
    float inv_n = 1.0f / (float)n;

    #pragma unroll
    for (int i = 0; i < 16; ++i) {
        int t = i * 1024 + tid;
        int mm = min(t, Mm - t);
        int ph = (mm * mm) % two_n;
        float sn, cs; __sincosf(PI_F * (float)ph * inv_n, &sn, &cs);
        L[bigidx(t >> 7, t & 127)] = make_float2(cs, sn);   // exp(+i b_phase)
    }
    __syncthreads();
    #pragma unroll
    for (int c0 = 0; c0 < 128; c0 += 64) {
        int t1 = c0 + f;
        float2 v[8];
        #pragma unroll
        for (int q = 0; q < 8; ++q) v[q] = L[bigidx(p + 16*q, t1)];
        dif128<true>(v, L, t1, p);
        int bb = p >> 1, r = p & 1;
        #pragma unroll
        for (int s = 0; s < 8; ++s) {
            int j = 16*bb + r + 2*s;
            int k2 = __brev((unsigned)j) >> 25;
            float sn, cs;
            __sincosf(-TWO_PI_F * (float)(t1 * k2) * (1.0f/16384.0f), &sn, &cs);
            L[bigidx(j, t1)] = cmul(v[s], make_float2(cs, sn));
        }
    }
    __syncthreads();
    #pragma unroll
    for (int r0 = 0; r0 < 128; r0 += 64) {
        int j = r0 + f;
        float2 v[8];
        #pragma unroll
        for (int q = 0; q < 8; ++q) v[q] = L[bigidx(j, p + 16*q)];
        dif128<false>(v, L, j, p);
        float2* bo = bhat + ((size_t)b << 14) + (j << 7) + (p << 3);
        #pragma unroll
        for (int s = 0; s < 8; ++s) bo[s] = v[s];
    }
}

// ------- main: 256 blocks = (cpair, b); 2 channels per block (rr loop) -----
// cpair*64+b => all 4 cpair-siblings of a batch land on the same XCD
// (64 % 8 == 0) and ALL 256 blocks are co-resident in one dispatch round,
// so x-lines are fetched once per XCD and partial out-lines merge in L2.
__global__ __launch_bounds__(1024, 1) void eofft_main(const float* __restrict__ x,
                                                      const float* __restrict__ rpm,
                                                      const float2* __restrict__ bhat,
                                                      float* __restrict__ out) {
    extern __shared__ float2 L[];
    __shared__ float2 sWhi[128];
    __shared__ float2 sWlo[128];
    int tid = threadIdx.x;
    int f = tid >> 4, p = tid & 15;      // f in [0,64)
    int bb = p >> 1, r = p & 1;
    int b = blockIdx.x & 63;
    int cpair = blockIdx.x >> 6;         // 0..3

    if (tid < 128) {
        float sn, cs; __sincosf(PI_F * (float)tid * (1.0f/64.0f), &sn, &cs);
        sWhi[tid] = make_float2(cs, -sn);
    } else if (tid < 256) {
        int m = tid - 128;
        float sn, cs; __sincosf(PI_F * (float)m * (1.0f/8192.0f), &sn, &cs);
        sWlo[m] = make_float2(cs, -sn);
    }
    int n = compute_n(rpm[b]);
    int two_n = 2 * n;
    float inv_n = 1.0f / (float)n;

    for (int rr = 0; rr < 2; ++rr) {
        int ch = cpair * 2 + rr;
        __syncthreads();   // L free of previous row's readers; orders tables
        // ---- build a = x*exp(-i a_phase) via quadratic-phase recurrence
        // (t steps by 1024: d=(t+1024)^2-t^2 = 2048t+1048576; dd step 2097152)
        {
            float sn, cs;
            __sincosf(PI_F * (float)((tid * tid) % two_n) * inv_n, &sn, &cs);
            float2 u = make_float2(cs, -sn);
            __sincosf(PI_F * (float)((2048 * tid + 1048576) % two_n) * inv_n, &sn, &cs);
            float2 dd = make_float2(cs, -sn);
            __sincosf(PI_F * (float)(2097152 % two_n) * inv_n, &sn, &cs);
            float2 Cst = make_float2(cs, -sn);
            const float* xb = x + ((size_t)b << 16) + ch;
            #pragma unroll
            for (int i = 0; i < 8; ++i) {
                int t = i * 1024 + tid;              // t < 8192
                float xv = xb[(size_t)t << 3];
                L[bigidx(t >> 7, t & 127)] = make_float2(xv * u.x, xv * u.y);
                u = cmul(u, dd); dd = cmul(dd, Cst);
            }
        }
        __syncthreads();
        // ---- phase A: fwd FFT over t2 per column t1; twiddle chain; bitrev row
        #pragma unroll
        for (int c0 = 0; c0 < 128; c0 += 64) {
            int t1 = c0 + f;
            float2 v[8];
            #pragma unroll
            for (int q = 0; q < 4; ++q) v[q] = L[bigidx(p + 16*q, t1)];
            difS<true, true>(v, L, t1, p, sWhi);
            int k2base = __brev((unsigned)(16*bb + r)) >> 25;
            float2 cur = wtab(sWhi, sWlo, t1 * k2base);
            float2 w8  = wtab(sWhi, sWlo, 8 * t1);
            #pragma unroll
            for (int e = 0; e < 8; ++e) {
                const int s = ((e & 1) << 2) | (e & 2) | ((e & 4) >> 2); // brev3(e)
                L[bigidx(16*bb + r + 2*s, t1)] = cmul(v[s], cur);
                cur = cmul(cur, w8);
            }
        }
        __syncthreads();
        // ---- phase B: per row j: fwd over t1, *Bhat, inv over k1, twiddle
        #pragma unroll
        for (int r0 = 0; r0 < 128; r0 += 64) {
            int j = r0 + f;
            float2 v[8];
            #pragma unroll
            for (int q = 0; q < 8; ++q) v[q] = L[bigidx(j, p + 16*q)];
            difS<false, false>(v, L, j, p, sWhi);
            {
                const float2* bhp = bhat + ((size_t)b << 14) + ((size_t)j << 7) + (p << 3);
                float2 bh[8];
                #pragma unroll
                for (int s = 0; s < 8; ++s) bh[s] = bhp[s];
                #pragma unroll
                for (int s = 0; s < 8; ++s) v[s] = cmul(v[s], bh[s]);
            }
            ditS<false, false>(v, L, j, p, sWhi);
            int k2v = __brev((unsigned)j) >> 25;
            float2 cur = wtab(sWhi, sWlo, k2v * p);
            float2 w16 = wtab(sWhi, sWlo, 16 * k2v);
            #pragma unroll
            for (int q = 0; q < 8; ++q) {
                // * exp(+2pi i k2 t1/M) = conj(cur)
                L[bigidx(j, p + 16*q)] = cmul(v[q], make_float2(cur.x, -cur.y));
                cur = cmul(cur, w16);
            }
        }
        __syncthreads();
        // ---- phase C: inverse FFT over k2 per column; keep t2 < 64; |.|/M
        #pragma unroll
        for (int c0 = 0; c0 < 128; c0 += 64) {
            int t1 = c0 + f;
            float2 v[8];
            #pragma unroll
            for (int s = 0; s < 8; ++s) v[s] = L[bigidx(16*bb + r + 2*s, t1)];
            ditS<true, true>(v, L, t1, p, sWhi);
            float* ob = out + (((size_t)(b << 13) + t1) << 3) + ch;
            #pragma unroll
            for (int q = 0; q < 4; ++q) {
                int t2 = p + 16*q;
                float2 z = v[q];
                ob[(size_t)t2 << 10] = sqrtf(z.x*z.x + z.y*z.y) * (1.0f/16384.0f);
            }
        }
    }
}

// ---------------- launch ----------------
extern "C" void kernel_launch(void* const* d_in, const int* in_sizes, int n_in,
                              void* d_out, int out_size, void* d_ws, size_t ws_size,
                              hipStream_t stream) {
    const float* x   = (const float*)d_in[0];
    const float* rpm = (const float*)d_in[1];
    float* outF = (float*)d_out;
    float2* bhat = (float2*)d_ws;                    // 64*16384 float2 = 8 MiB

    eofft_bhat<<<Bn, 1024, 131072, stream>>>(rpm, bhat);
    eofft_main<<<Bn * 4, 1024, 131072, stream>>>(x, rpm, bhat, outF);
}

// Round 9
// 94.302 us; speedup vs baseline: 2.8745x; 2.8745x over previous
//
#include <hip/hip_runtime.h>
#include <math.h>

// EngineOrderFFT via batched Bluestein. |X| = |conv[:, :K]|. M=16384 as a
// 128x128 four-step across 3 data kernels with LINE-COMPLETE global I/O:
// every block owns all 8 channels of its t1/j range, so every x-line is
// fetched once and every out-line is written once (no inter-block L2 merge
// dependence -- the R4-R7 amplification trap). Intermediates W1/S2 are
// contiguous-chunked via small LDS staging buffers.
//   W1[b][j][t1][ch], S2[b][t1][j][ch]  (float2; j = bitrev position)
//   bhat[b][j][reg-octet] parked in d_out (dead until K3 writes).

static constexpr int Bn = 64;

#define PI_F 3.14159265358979323846f
#define TWO_PI_F 6.28318530717958647692f
#define R2_F 0.70710678118654752f

__device__ __forceinline__ int compute_n(float rpm) {
    // ref: pad = floor((40*60/rpm - 1)*8192) in f32; n = 8192 + pad
    return 8192 + (int)floorf((2400.0f / rpm - 1.0f) * 8192.0f);
}
__device__ __forceinline__ float2 cmul(float2 a, float2 b) {
    return make_float2(a.x*b.x - a.y*b.y, a.x*b.y + a.y*b.x);
}
__device__ __forceinline__ float2 cadd(float2 a, float2 b){ return make_float2(a.x+b.x, a.y+b.y); }
__device__ __forceinline__ float2 csub(float2 a, float2 b){ return make_float2(a.x-b.x, a.y-b.y); }
__device__ __forceinline__ float2 shflx1(float2 v) {
    return make_float2(__shfl_xor(v.x, 1, 64), __shfl_xor(v.y, 1, 64));
}
__device__ __forceinline__ int brev7(int x) { return (int)(__brev((unsigned)x) >> 25); }

#define BF(lo,hi,tw) { float2 _d = csub(lo,hi); lo = cadd(lo,hi); hi = cmul(_d, tw); }
#define BT(lo,hi,tw) { float2 _b = cmul(hi,tw); hi = csub(lo,_b); lo = cadd(lo,_b); }
#define SELC(r,c0,s0,c1,s1) ((r) ? make_float2(c1,s1) : make_float2(c0,s0))
#define IDX(u) ((u) + ((u) >> 4))          // row-local pad (R2/R3-proven)

// W_M^{-m}: Whi[m]=exp(-i*pi*m/64), Wlo[m]=exp(-i*pi*m/8192)
__device__ __forceinline__ float2 wtab(const float2* Whi, const float2* Wlo, int m) {
    return cmul(Whi[m >> 7], Wlo[m & 127]);
}

// ====== full-tile swizzled addressing (bhat builder only, R3-proven) ======
__device__ __forceinline__ int bigidx(int r, int c) {
    int sw = ((r & 15) ^ ((r >> 4) << 1) ^ ((c >> 4) << 1)) & 15;
    return (r << 7) + (c ^ sw);
}
template<bool COL>
__device__ __forceinline__ int taddr(int w, int u) {
    return COL ? bigidx(u, w) : bigidx(w, u);
}
template<bool COL>
__device__ __forceinline__ void dif128(float2 v[8], float2* L, int w, int p) {
    float sn, cs;
    __sincosf(PI_F * (float)p * (1.0f/64.0f), &sn, &cs);
    float2 w1 = make_float2(cs, -sn);
    float2 w2 = cmul(w1, w1);
    float2 w4 = cmul(w2, w2);
    BF(v[0],v[4], w1);
    BF(v[1],v[5], cmul(w1, make_float2(R2_F,-R2_F)));
    BF(v[2],v[6], make_float2(w1.y, -w1.x));
    BF(v[3],v[7], cmul(w1, make_float2(-R2_F,-R2_F)));
    float2 w2i = make_float2(w2.y, -w2.x);
    BF(v[0],v[2], w2);  BF(v[1],v[3], w2i);
    BF(v[4],v[6], w2);  BF(v[5],v[7], w2i);
    BF(v[0],v[1], w4);  BF(v[2],v[3], w4);
    BF(v[4],v[5], w4);  BF(v[6],v[7], w4);
    #pragma unroll
    for (int q = 0; q < 8; ++q) L[taddr<COL>(w, p + 16*q)] = v[q];
    int bb = p >> 1, r = p & 1;
    #pragma unroll
    for (int s = 0; s < 8; ++s) v[s] = L[taddr<COL>(w, 16*bb + r + 2*s)];
    BF(v[0],v[4], SELC(r, 1.f,0.f,                    0.92387953f,-0.38268343f));
    BF(v[1],v[5], SELC(r, 0.70710678f,-0.70710678f,   0.38268343f,-0.92387953f));
    BF(v[2],v[6], SELC(r, 0.f,-1.f,                  -0.38268343f,-0.92387953f));
    BF(v[3],v[7], SELC(r, -0.70710678f,-0.70710678f, -0.92387953f,-0.38268343f));
    BF(v[0],v[2], SELC(r, 1.f,0.f,  0.70710678f,-0.70710678f));
    BF(v[1],v[3], SELC(r, 0.f,-1.f, -0.70710678f,-0.70710678f));
    BF(v[4],v[6], SELC(r, 1.f,0.f,  0.70710678f,-0.70710678f));
    BF(v[5],v[7], SELC(r, 0.f,-1.f, -0.70710678f,-0.70710678f));
    #pragma unroll
    for (int s = 0; s < 8; s += 2) {
        float2 d = csub(v[s], v[s+1]);
        v[s] = cadd(v[s], v[s+1]);
        v[s+1] = r ? make_float2(d.y, -d.x) : d;
    }
    #pragma unroll
    for (int s = 0; s < 8; ++s) {
        float2 o = shflx1(v[s]);
        v[s] = r ? csub(o, v[s]) : cadd(v[s], o);
    }
}

// ====== row-local cores (data kernels). Lf = per-FFT region (>=137 f2) ======
// HZ: inputs v[4..7] are implicit zeros (not loaded).
template<bool HZ>
__device__ __forceinline__ void difR(float2 v[8], float2* Lf, int p,
                                     const float2* sWhi) {
    float2 w1 = sWhi[p];                        // exp(-i*pi*p/64)
    float2 w2 = cmul(w1, w1);
    float2 w4 = cmul(w2, w2);
    float2 w1b = cmul(w1, make_float2(R2_F,-R2_F));
    float2 w1c = make_float2(w1.y, -w1.x);
    float2 w1d = cmul(w1, make_float2(-R2_F,-R2_F));
    float2 w2i = make_float2(w2.y, -w2.x);
    if (HZ) {
        v[4] = cmul(v[0], w1);
        v[5] = cmul(v[1], w1b);
        v[6] = cmul(v[2], w1c);
        v[7] = cmul(v[3], w1d);
    } else {
        BF(v[0],v[4], w1);
        BF(v[1],v[5], w1b);
        BF(v[2],v[6], w1c);
        BF(v[3],v[7], w1d);
    }
    BF(v[0],v[2], w2);  BF(v[1],v[3], w2i);
    BF(v[4],v[6], w2);  BF(v[5],v[7], w2i);
    BF(v[0],v[1], w4);  BF(v[2],v[3], w4);
    BF(v[4],v[5], w4);  BF(v[6],v[7], w4);
    #pragma unroll
    for (int q = 0; q < 8; ++q) Lf[IDX(p + 16*q)] = v[q];
    int bb = p >> 1, r = p & 1;
    #pragma unroll
    for (int s = 0; s < 8; ++s) v[s] = Lf[IDX(16*bb + r + 2*s)];
    BF(v[0],v[4], SELC(r, 1.f,0.f,                    0.92387953f,-0.38268343f));
    BF(v[1],v[5], SELC(r, 0.70710678f,-0.70710678f,   0.38268343f,-0.92387953f));
    BF(v[2],v[6], SELC(r, 0.f,-1.f,                  -0.38268343f,-0.92387953f));
    BF(v[3],v[7], SELC(r, -0.70710678f,-0.70710678f, -0.92387953f,-0.38268343f));
    BF(v[0],v[2], SELC(r, 1.f,0.f,  0.70710678f,-0.70710678f));
    BF(v[1],v[3], SELC(r, 0.f,-1.f, -0.70710678f,-0.70710678f));
    BF(v[4],v[6], SELC(r, 1.f,0.f,  0.70710678f,-0.70710678f));
    BF(v[5],v[7], SELC(r, 0.f,-1.f, -0.70710678f,-0.70710678f));
    #pragma unroll
    for (int s = 0; s < 8; s += 2) {
        float2 d = csub(v[s], v[s+1]);
        v[s] = cadd(v[s], v[s+1]);
        v[s+1] = r ? make_float2(d.y, -d.x) : d;
    }
    #pragma unroll
    for (int s = 0; s < 8; ++s) {
        float2 o = shflx1(v[s]);
        v[s] = r ? csub(o, v[s]) : cadd(v[s], o);
    }
}

// HOUT: only lo outputs v[0..3] of the final stage are produced.
template<bool HOUT>
__device__ __forceinline__ void ditR(float2 v[8], float2* Lf, int p,
                                     const float2* sWhi) {
    int bb = p >> 1, r = p & 1;
    #pragma unroll
    for (int s = 0; s < 8; ++s) {
        float2 o = shflx1(v[s]);
        v[s] = r ? csub(o, v[s]) : cadd(v[s], o);
    }
    #pragma unroll
    for (int s = 0; s < 8; s += 2) {
        float2 bq = v[s+1];
        if (r) bq = make_float2(-bq.y, bq.x);
        v[s+1] = csub(v[s], bq);
        v[s] = cadd(v[s], bq);
    }
    BT(v[0],v[2], SELC(r, 1.f,0.f,  0.70710678f,0.70710678f));
    BT(v[1],v[3], SELC(r, 0.f,1.f, -0.70710678f,0.70710678f));
    BT(v[4],v[6], SELC(r, 1.f,0.f,  0.70710678f,0.70710678f));
    BT(v[5],v[7], SELC(r, 0.f,1.f, -0.70710678f,0.70710678f));
    BT(v[0],v[4], SELC(r, 1.f,0.f,                   0.92387953f,0.38268343f));
    BT(v[1],v[5], SELC(r, 0.70710678f,0.70710678f,   0.38268343f,0.92387953f));
    BT(v[2],v[6], SELC(r, 0.f,1.f,                  -0.38268343f,0.92387953f));
    BT(v[3],v[7], SELC(r, -0.70710678f,0.70710678f, -0.92387953f,0.38268343f));
    #pragma unroll
    for (int s = 0; s < 8; ++s) Lf[IDX(16*bb + r + 2*s)] = v[s];
    #pragma unroll
    for (int q = 0; q < 8; ++q) v[q] = Lf[IDX(p + 16*q)];
    float2 w1 = make_float2(sWhi[p].x, -sWhi[p].y);   // exp(+i*pi*p/64)
    float2 w2 = cmul(w1, w1);
    float2 w4 = cmul(w2, w2);
    float2 w2j = make_float2(-w2.y, w2.x);
    float2 w1b = cmul(w1, make_float2(R2_F, R2_F));
    float2 w1c = make_float2(-w1.y, w1.x);
    float2 w1d = cmul(w1, make_float2(-R2_F, R2_F));
    BT(v[0],v[1], w4); BT(v[2],v[3], w4);
    BT(v[4],v[5], w4); BT(v[6],v[7], w4);
    BT(v[0],v[2], w2);  BT(v[1],v[3], w2j);
    BT(v[4],v[6], w2);  BT(v[5],v[7], w2j);
    if (HOUT) {
        v[0] = cadd(v[0], cmul(v[4], w1));
        v[1] = cadd(v[1], cmul(v[5], w1b));
        v[2] = cadd(v[2], cmul(v[6], w1c));
        v[3] = cadd(v[3], cmul(v[7], w1d));
    } else {
        BT(v[0],v[4], w1);
        BT(v[1],v[5], w1b);
        BT(v[2],v[6], w1c);
        BT(v[3],v[7], w1d);
    }
}

__device__ __forceinline__ void load_tabs(float2* sWhi, float2* sWlo, int tid) {
    if (tid < 128) {
        float sn, cs; __sincosf(PI_F * (float)tid * (1.0f/64.0f), &sn, &cs);
        sWhi[tid] = make_float2(cs, -sn);
    } else if (tid < 256) {
        int m = tid - 128;
        float sn, cs; __sincosf(PI_F * (float)m * (1.0f/8192.0f), &sn, &cs);
        sWlo[m] = make_float2(cs, -sn);
    }
}

// ---------------- Bhat builder: one block per b (R3-R7-proven) ------
__global__ __launch_bounds__(1024) void eofft_bhat(const float* __restrict__ rpm,
                                                   float2* __restrict__ bhat) {
    extern __shared__ float2 L[];
    int tid = threadIdx.x;
    int f = tid >> 4, p = tid & 15;
    int b = blockIdx.x;
    int n = compute_n(rpm[b]);
    int two_n = 2 * n;
    float inv_n = 1.0f / (float)n;

    #pragma unroll
    for (int i = 0; i < 16; ++i) {
        int t = i * 1024 + tid;
        int mm = min(t, 16384 - t);
        int ph = (mm * mm) % two_n;
        float sn, cs; __sincosf(PI_F * (float)ph * inv_n, &sn, &cs);
        L[bigidx(t >> 7, t & 127)] = make_float2(cs, sn);   // exp(+i b_phase)
    }
    __syncthreads();
    #pragma unroll
    for (int c0 = 0; c0 < 128; c0 += 64) {
        int t1 = c0 + f;
        float2 v[8];
        #pragma unroll
        for (int q = 0; q < 8; ++q) v[q] = L[bigidx(p + 16*q, t1)];
        dif128<true>(v, L, t1, p);
        int bb = p >> 1, r = p & 1;
        #pragma unroll
        for (int s = 0; s < 8; ++s) {
            int j = 16*bb + r + 2*s;
            int k2 = brev7(j);
            float sn, cs;
            __sincosf(-TWO_PI_F * (float)(t1 * k2) * (1.0f/16384.0f), &sn, &cs);
            L[bigidx(j, t1)] = cmul(v[s], make_float2(cs, sn));
        }
    }
    __syncthreads();
    #pragma unroll
    for (int r0 = 0; r0 < 128; r0 += 64) {
        int j = r0 + f;
        float2 v[8];
        #pragma unroll
        for (int q = 0; q < 8; ++q) v[q] = L[bigidx(j, p + 16*q)];
        dif128<false>(v, L, j, p);
        float2* bo = bhat + ((size_t)b << 14) + (j << 7) + (p << 3);
        #pragma unroll
        for (int s = 0; s < 8; ++s) bo[s] = v[s];
    }
}

// ---- K1: block=(b, t1-pair). x -> chirp -> FFT over t2 -> twiddle -> W1 ----
__global__ __launch_bounds__(256) void k1(const float* __restrict__ x,
                                          const float* __restrict__ rpm,
                                          float2* __restrict__ w1) {
    __shared__ float2 Lw[16 * 137];
    __shared__ float2 Ls[128 * 17];
    __shared__ float2 chirpT[128];
    __shared__ float2 sWhi[128];
    __shared__ float2 sWlo[128];
    int tid = threadIdx.x;
    int g = tid >> 4, p = tid & 15;
    int bb = p >> 1, r = p & 1;
    int b = blockIdx.x >> 6;
    int t1_0 = (blockIdx.x & 63) << 1;

    load_tabs(sWhi, sWlo, tid);
    int n = compute_n(rpm[b]);
    int two_n = 2 * n;
    float inv_n = 1.0f / (float)n;
    if (tid < 128) {
        int t2 = tid >> 1, t1l = tid & 1;
        int t = t1_0 + t1l + (t2 << 7);
        int ph = (t * t) % two_n;
        float sn, cs; __sincosf(PI_F * (float)ph * inv_n, &sn, &cs);
        chirpT[tid] = make_float2(cs, -sn);     // exp(-i a_phase)
    }
    __syncthreads();
    // load x (line-complete 64B chunks), chirp-modulate, scatter to cols
    {
        const float2* xb2 = (const float2*)(x + ((size_t)b << 16));
        #pragma unroll
        for (int i = 0; i < 2; ++i) {
            int l = i * 256 + tid;              // l < 512
            int t2 = l >> 3, w = l & 7;
            int t1l = w >> 2, cp = w & 3;
            float2 xv = xb2[(size_t)(t1_0 + t1l + (t2 << 7)) * 4 + cp];
            float2 u = chirpT[t2 * 2 + t1l];
            int c = t1l * 8 + cp * 2;
            Lw[c * 137 + IDX(t2)]       = make_float2(xv.x * u.x, xv.x * u.y);
            Lw[(c + 1) * 137 + IDX(t2)] = make_float2(xv.y * u.x, xv.y * u.y);
        }
    }
    __syncthreads();
    // 16 column FFTs over t2 (col c = g = t1l*8+ch), twiddle chain, stage
    {
        float2 v[8];
        #pragma unroll
        for (int q = 0; q < 4; ++q) v[q] = Lw[g * 137 + IDX(p + 16*q)];
        difR<true>(v, Lw + g * 137, p, sWhi);
        int t1 = t1_0 + (g >> 3);
        int k2base = brev7(16*bb + r);
        float2 cur = wtab(sWhi, sWlo, t1 * k2base);
        float2 w8  = wtab(sWhi, sWlo, 8 * t1);
        #pragma unroll
        for (int e = 0; e < 8; ++e) {
            const int s = ((e & 1) << 2) | (e & 2) | ((e & 4) >> 2); // brev3(e)
            Ls[(16*bb + r + 2*s) * 17 + g] = cmul(v[s], cur);
            cur = cmul(cur, w8);
        }
    }
    __syncthreads();
    // copy out: per j a contiguous 128B chunk of W1[b][j][t1pair][ch]
    {
        float2* wb = w1 + ((size_t)b << 17) + (t1_0 << 3);
        #pragma unroll
        for (int i = 0; i < 8; ++i) {
            int l = i * 256 + tid;              // l < 2048
            int j = l >> 4, w = l & 15;
            wb[((size_t)j << 10) + w] = Ls[j * 17 + w];
        }
    }
}

// ---- K2: block=(b, 4-j-slice). W1 -> FFT over t1 -> *Bhat -> iFFT -> S2 ----
__global__ __launch_bounds__(512) void k2(const float2* __restrict__ w1,
                                          const float2* __restrict__ bhat,
                                          float2* __restrict__ s2) {
    __shared__ float2 Lw[32 * 137];
    __shared__ float2 Ls[128 * 33];
    __shared__ float2 sWhi[128];
    __shared__ float2 sWlo[128];
    int tid = threadIdx.x;
    int g = tid >> 4, p = tid & 15;             // g in [0,32)
    int b = blockIdx.x >> 5;
    int j0 = (blockIdx.x & 31) << 2;

    load_tabs(sWhi, sWlo, tid);
    __syncthreads();
    // load 32 rows (jl,ch) x 128 t1: contiguous 32 KB
    {
        const float2* rb = w1 + ((size_t)b << 17) + ((size_t)j0 << 10);
        #pragma unroll
        for (int i = 0; i < 8; ++i) {
            int l = i * 512 + tid;              // l < 4096
            int jl = l >> 10, t1 = (l >> 3) & 127, ch = l & 7;
            Lw[(jl * 8 + ch) * 137 + IDX(t1)] = rb[l];
        }
    }
    __syncthreads();
    {
        float2* Lf = Lw + g * 137;
        float2 v[8];
        #pragma unroll
        for (int q = 0; q < 8; ++q) v[q] = Lf[IDX(p + 16*q)];
        difR<false>(v, Lf, p, sWhi);
        int j = j0 + (g >> 3);
        const float2* bhp = bhat + ((size_t)b << 14) + (j << 7) + (p << 3);
        #pragma unroll
        for (int s = 0; s < 8; ++s) v[s] = cmul(v[s], bhp[s]);
        ditR<false>(v, Lf, p, sWhi);
        int k2v = brev7(j);
        float2 cur = wtab(sWhi, sWlo, k2v * p);
        float2 w16 = wtab(sWhi, sWlo, 16 * k2v);
        #pragma unroll
        for (int q = 0; q < 8; ++q) {
            // * exp(+2pi i k2 t1/M) = conj(cur); stage transposed [t1][row]
            Ls[(p + 16*q) * 33 + g] = cmul(v[q], make_float2(cur.x, -cur.y));
            cur = cmul(cur, w16);
        }
    }
    __syncthreads();
    // copy out: per t1 a contiguous 256B chunk of S2[b][t1][jslice][ch]
    {
        float2* sb = s2 + ((size_t)b << 17) + (j0 << 3);
        #pragma unroll
        for (int i = 0; i < 8; ++i) {
            int l = i * 512 + tid;              // l < 4096
            int t1 = l >> 5, w = l & 31;
            sb[((size_t)t1 << 10) + w] = Ls[t1 * 33 + w];
        }
    }
}

// ---- K3: block=(b, t1-pair). S2 -> iFFT over j -> |.|/M -> out ----
__global__ __launch_bounds__(256) void k3(const float2* __restrict__ s2,
                                          float* __restrict__ outF) {
    __shared__ float2 Lw[16 * 137];
    __shared__ float Lsf[64 * 20 + 16];
    __shared__ float2 sWhi[128];
    __shared__ float2 sWlo[128];
    int tid = threadIdx.x;
    int g = tid >> 4, p = tid & 15;
    int bb = p >> 1, r = p & 1;
    int b = blockIdx.x >> 6;
    int t1_0 = (blockIdx.x & 63) << 1;

    load_tabs(sWhi, sWlo, tid);
    __syncthreads();
    // load 2 t1 x 128 j x 8 ch: contiguous 16 KB
    {
        const float2* rb = s2 + ((size_t)b << 17) + ((size_t)t1_0 << 10);
        #pragma unroll
        for (int i = 0; i < 8; ++i) {
            int l = i * 256 + tid;              // l < 2048
            int t1l = l >> 10, j = (l >> 3) & 127, ch = l & 7;
            Lw[(t1l * 8 + ch) * 137 + IDX(j)] = rb[l];
        }
    }
    __syncthreads();
    {
        float2* Lf = Lw + g * 137;
        float2 v[8];
        #pragma unroll
        for (int s = 0; s < 8; ++s) v[s] = Lf[IDX(16*bb + r + 2*s)];
        ditR<true>(v, Lf, p, sWhi);
        // v[q] = z[m = t1 + 128*(p+16q)], q<4; stage |.|/M as floats
        #pragma unroll
        for (int q = 0; q < 4; ++q) {
            float2 z = v[q];
            Lsf[(p + 16*q) * 20 + g] = sqrtf(z.x*z.x + z.y*z.y) * (1.0f/16384.0f);
        }
    }
    __syncthreads();
    // copy out: per t2 a line-complete 64B chunk of out[b][m][ch]
    {
        float* ob = outF + ((size_t)b << 16) + (t1_0 << 3);
        #pragma unroll
        for (int i = 0; i < 4; ++i) {
            int l = i * 256 + tid;              // l < 1024
            int t2 = l >> 4, w = l & 15;
            ob[((size_t)t2 << 10) + w] = Lsf[t2 * 20 + w];
        }
    }
}

// ---------------- launch ----------------
extern "C" void kernel_launch(void* const* d_in, const int* in_sizes, int n_in,
                              void* d_out, int out_size, void* d_ws, size_t ws_size,
                              hipStream_t stream) {
    const float* x   = (const float*)d_in[0];
    const float* rpm = (const float*)d_in[1];
    float* outF = (float*)d_out;
    float2* w1   = (float2*)d_ws;                        // 64 MiB
    float2* s2   = w1 + (size_t)Bn * 131072;             // 64 MiB
    float2* bhat = (float2*)d_out;                       // 8 MiB, dead before k3

    eofft_bhat<<<Bn, 1024, 131072, stream>>>(rpm, bhat);
    k1<<<Bn * 64, 256, 0, stream>>>(x, rpm, w1);
    k2<<<Bn * 32, 512, 0, stream>>>(w1, bhat, s2);
    k3<<<Bn * 64, 256, 0, stream>>>(s2, outF);
}

// Round 10
// 83.789 us; speedup vs baseline: 3.2352x; 1.1255x over previous
//
#include <hip/hip_runtime.h>
#include <hip/hip_fp16.h>
#include <math.h>

// EngineOrderFFT via batched Bluestein. |X| = |conv[:, :K]|. M=16384 as a
// 128x128 four-step, 5 kernels, ALL line-complete global I/O (R8-proven).
// R9: (a) W1/S2 intermediates stored fp16 (__half2 per complex) -- halves
// the dominant ledger; 1/16384 folded into k2's output twiddle keeps S2 in
// fp16 range; (b) bhat builder split into two line-complete 256-thr kernels
// (p1/p2) replacing the serial 64x(128KB-LDS) monolith.
//   W1[b][j][t1][ch] (half2), S2[b][t1][j][ch] (half2, pre-scaled 1/M)
//   W1c[b][j][t1] (float2, chirp temp), bhat[b][j][reg-octet] (float2, d_out)

static constexpr int Bn = 64;

#define PI_F 3.14159265358979323846f
#define TWO_PI_F 6.28318530717958647692f
#define R2_F 0.70710678118654752f

__device__ __forceinline__ int compute_n(float rpm) {
    // ref: pad = floor((40*60/rpm - 1)*8192) in f32; n = 8192 + pad
    return 8192 + (int)floorf((2400.0f / rpm - 1.0f) * 8192.0f);
}
__device__ __forceinline__ float2 cmul(float2 a, float2 b) {
    return make_float2(a.x*b.x - a.y*b.y, a.x*b.y + a.y*b.x);
}
__device__ __forceinline__ float2 cadd(float2 a, float2 b){ return make_float2(a.x+b.x, a.y+b.y); }
__device__ __forceinline__ float2 csub(float2 a, float2 b){ return make_float2(a.x-b.x, a.y-b.y); }
__device__ __forceinline__ float2 shflx1(float2 v) {
    return make_float2(__shfl_xor(v.x, 1, 64), __shfl_xor(v.y, 1, 64));
}
__device__ __forceinline__ int brev7(int x) { return (int)(__brev((unsigned)x) >> 25); }

#define BF(lo,hi,tw) { float2 _d = csub(lo,hi); lo = cadd(lo,hi); hi = cmul(_d, tw); }
#define BT(lo,hi,tw) { float2 _b = cmul(hi,tw); hi = csub(lo,_b); lo = cadd(lo,_b); }
#define SELC(r,c0,s0,c1,s1) ((r) ? make_float2(c1,s1) : make_float2(c0,s0))
#define IDX(u) ((u) + ((u) >> 4))          // row-local pad (R2/R3-proven)

// W_M^{-m}: Whi[m]=exp(-i*pi*m/64), Wlo[m]=exp(-i*pi*m/8192)
__device__ __forceinline__ float2 wtab(const float2* Whi, const float2* Wlo, int m) {
    return cmul(Whi[m >> 7], Wlo[m & 127]);
}

// ====== row-local cores (all kernels). Lf = per-FFT region (>=137 f2) ======
// HZ: inputs v[4..7] are implicit zeros (not loaded).
template<bool HZ>
__device__ __forceinline__ void difR(float2 v[8], float2* Lf, int p,
                                     const float2* sWhi) {
    float2 w1 = sWhi[p];                        // exp(-i*pi*p/64)
    float2 w2 = cmul(w1, w1);
    float2 w4 = cmul(w2, w2);
    float2 w1b = cmul(w1, make_float2(R2_F,-R2_F));
    float2 w1c = make_float2(w1.y, -w1.x);
    float2 w1d = cmul(w1, make_float2(-R2_F,-R2_F));
    float2 w2i = make_float2(w2.y, -w2.x);
    if (HZ) {
        v[4] = cmul(v[0], w1);
        v[5] = cmul(v[1], w1b);
        v[6] = cmul(v[2], w1c);
        v[7] = cmul(v[3], w1d);
    } else {
        BF(v[0],v[4], w1);
        BF(v[1],v[5], w1b);
        BF(v[2],v[6], w1c);
        BF(v[3],v[7], w1d);
    }
    BF(v[0],v[2], w2);  BF(v[1],v[3], w2i);
    BF(v[4],v[6], w2);  BF(v[5],v[7], w2i);
    BF(v[0],v[1], w4);  BF(v[2],v[3], w4);
    BF(v[4],v[5], w4);  BF(v[6],v[7], w4);
    #pragma unroll
    for (int q = 0; q < 8; ++q) Lf[IDX(p + 16*q)] = v[q];
    int bb = p >> 1, r = p & 1;
    #pragma unroll
    for (int s = 0; s < 8; ++s) v[s] = Lf[IDX(16*bb + r + 2*s)];
    BF(v[0],v[4], SELC(r, 1.f,0.f,                    0.92387953f,-0.38268343f));
    BF(v[1],v[5], SELC(r, 0.70710678f,-0.70710678f,   0.38268343f,-0.92387953f));
    BF(v[2],v[6], SELC(r, 0.f,-1.f,                  -0.38268343f,-0.92387953f));
    BF(v[3],v[7], SELC(r, -0.70710678f,-0.70710678f, -0.92387953f,-0.38268343f));
    BF(v[0],v[2], SELC(r, 1.f,0.f,  0.70710678f,-0.70710678f));
    BF(v[1],v[3], SELC(r, 0.f,-1.f, -0.70710678f,-0.70710678f));
    BF(v[4],v[6], SELC(r, 1.f,0.f,  0.70710678f,-0.70710678f));
    BF(v[5],v[7], SELC(r, 0.f,-1.f, -0.70710678f,-0.70710678f));
    #pragma unroll
    for (int s = 0; s < 8; s += 2) {
        float2 d = csub(v[s], v[s+1]);
        v[s] = cadd(v[s], v[s+1]);
        v[s+1] = r ? make_float2(d.y, -d.x) : d;
    }
    #pragma unroll
    for (int s = 0; s < 8; ++s) {
        float2 o = shflx1(v[s]);
        v[s] = r ? csub(o, v[s]) : cadd(v[s], o);
    }
}

// HOUT: only lo outputs v[0..3] of the final stage are produced.
template<bool HOUT>
__device__ __forceinline__ void ditR(float2 v[8], float2* Lf, int p,
                                     const float2* sWhi) {
    int bb = p >> 1, r = p & 1;
    #pragma unroll
    for (int s = 0; s < 8; ++s) {
        float2 o = shflx1(v[s]);
        v[s] = r ? csub(o, v[s]) : cadd(v[s], o);
    }
    #pragma unroll
    for (int s = 0; s < 8; s += 2) {
        float2 bq = v[s+1];
        if (r) bq = make_float2(-bq.y, bq.x);
        v[s+1] = csub(v[s], bq);
        v[s] = cadd(v[s], bq);
    }
    BT(v[0],v[2], SELC(r, 1.f,0.f,  0.70710678f,0.70710678f));
    BT(v[1],v[3], SELC(r, 0.f,1.f, -0.70710678f,0.70710678f));
    BT(v[4],v[6], SELC(r, 1.f,0.f,  0.70710678f,0.70710678f));
    BT(v[5],v[7], SELC(r, 0.f,1.f, -0.70710678f,0.70710678f));
    BT(v[0],v[4], SELC(r, 1.f,0.f,                   0.92387953f,0.38268343f));
    BT(v[1],v[5], SELC(r, 0.70710678f,0.70710678f,   0.38268343f,0.92387953f));
    BT(v[2],v[6], SELC(r, 0.f,1.f,                  -0.38268343f,0.92387953f));
    BT(v[3],v[7], SELC(r, -0.70710678f,0.70710678f, -0.92387953f,0.38268343f));
    #pragma unroll
    for (int s = 0; s < 8; ++s) Lf[IDX(16*bb + r + 2*s)] = v[s];
    #pragma unroll
    for (int q = 0; q < 8; ++q) v[q] = Lf[IDX(p + 16*q)];
    float2 w1 = make_float2(sWhi[p].x, -sWhi[p].y);   // exp(+i*pi*p/64)
    float2 w2 = cmul(w1, w1);
    float2 w4 = cmul(w2, w2);
    float2 w2j = make_float2(-w2.y, w2.x);
    float2 w1b = cmul(w1, make_float2(R2_F, R2_F));
    float2 w1c = make_float2(-w1.y, w1.x);
    float2 w1d = cmul(w1, make_float2(-R2_F, R2_F));
    BT(v[0],v[1], w4); BT(v[2],v[3], w4);
    BT(v[4],v[5], w4); BT(v[6],v[7], w4);
    BT(v[0],v[2], w2);  BT(v[1],v[3], w2j);
    BT(v[4],v[6], w2);  BT(v[5],v[7], w2j);
    if (HOUT) {
        v[0] = cadd(v[0], cmul(v[4], w1));
        v[1] = cadd(v[1], cmul(v[5], w1b));
        v[2] = cadd(v[2], cmul(v[6], w1c));
        v[3] = cadd(v[3], cmul(v[7], w1d));
    } else {
        BT(v[0],v[4], w1);
        BT(v[1],v[5], w1b);
        BT(v[2],v[6], w1c);
        BT(v[3],v[7], w1d);
    }
}

__device__ __forceinline__ void load_tabs(float2* sWhi, float2* sWlo, int tid) {
    if (tid < 128) {
        float sn, cs; __sincosf(PI_F * (float)tid * (1.0f/64.0f), &sn, &cs);
        sWhi[tid] = make_float2(cs, -sn);
    } else if (tid < 256) {
        int m = tid - 128;
        float sn, cs; __sincosf(PI_F * (float)m * (1.0f/8192.0f), &sn, &cs);
        sWlo[m] = make_float2(cs, -sn);
    }
}

// ---- bhat p1: block=(b, 16-t1-group). chirp -> FFT over t2 -> twiddle -> W1c
__global__ __launch_bounds__(256) void bhat_p1(const float* __restrict__ rpm,
                                               float2* __restrict__ w1c) {
    __shared__ float2 Lw[16 * 137];
    __shared__ float2 Ls[128 * 17];
    __shared__ float2 sWhi[128];
    __shared__ float2 sWlo[128];
    int tid = threadIdx.x;
    int g = tid >> 4, p = tid & 15;
    int bb = p >> 1, r = p & 1;
    int b = blockIdx.x >> 3;
    int t1_0 = (blockIdx.x & 7) << 4;

    load_tabs(sWhi, sWlo, tid);
    int n = compute_n(rpm[b]);
    int two_n = 2 * n;
    float inv_n = 1.0f / (float)n;
    // build chirp: 16 cols x 128 t2
    #pragma unroll
    for (int i = 0; i < 8; ++i) {
        int l = i * 256 + tid;
        int t2 = l >> 4, c = l & 15;
        int t = (t1_0 + c) + (t2 << 7);
        int mm = min(t, 16384 - t);
        int ph = (mm * mm) % two_n;
        float sn, cs; __sincosf(PI_F * (float)ph * inv_n, &sn, &cs);
        Lw[c * 137 + IDX(t2)] = make_float2(cs, sn);   // exp(+i b_phase)
    }
    __syncthreads();
    {
        float2 v[8];
        #pragma unroll
        for (int q = 0; q < 8; ++q) v[q] = Lw[g * 137 + IDX(p + 16*q)];
        difR<false>(v, Lw + g * 137, p, sWhi);
        int t1 = t1_0 + g;
        int k2base = brev7(16*bb + r);
        float2 cur = wtab(sWhi, sWlo, t1 * k2base);
        float2 w8  = wtab(sWhi, sWlo, 8 * t1);
        #pragma unroll
        for (int e = 0; e < 8; ++e) {
            const int s = ((e & 1) << 2) | (e & 2) | ((e & 4) >> 2); // brev3(e)
            Ls[(16*bb + r + 2*s) * 17 + g] = cmul(v[s], cur);
            cur = cmul(cur, w8);
        }
    }
    __syncthreads();
    // copy out: W1c[b][j][t1], per j a 128B chunk
    {
        float2* wb = w1c + ((size_t)b << 14) + t1_0;
        #pragma unroll
        for (int i = 0; i < 8; ++i) {
            int l = i * 256 + tid;              // l < 2048
            int j = l >> 4, w = l & 15;
            wb[(j << 7) + w] = Ls[j * 17 + w];
        }
    }
}

// ---- bhat p2: block=(b, 16-j-group). FFT over t1 -> bhat register-order ----
__global__ __launch_bounds__(256) void bhat_p2(const float2* __restrict__ w1c,
                                               float2* __restrict__ bhat) {
    __shared__ float2 Lw[16 * 137];
    __shared__ float2 sWhi[128];
    __shared__ float2 sWlo[128];
    int tid = threadIdx.x;
    int g = tid >> 4, p = tid & 15;
    int b = blockIdx.x >> 3;
    int j0 = (blockIdx.x & 7) << 4;

    load_tabs(sWhi, sWlo, tid);
    {
        const float2* rb = w1c + ((size_t)b << 14) + ((size_t)j0 << 7);
        #pragma unroll
        for (int i = 0; i < 8; ++i) {
            int l = i * 256 + tid;              // l < 2048 (16 KB contiguous)
            Lw[(l >> 7) * 137 + IDX(l & 127)] = rb[l];
        }
    }
    __syncthreads();
    {
        float2 v[8];
        #pragma unroll
        for (int q = 0; q < 8; ++q) v[q] = Lw[g * 137 + IDX(p + 16*q)];
        difR<false>(v, Lw + g * 137, p, sWhi);
        float2* bo = bhat + ((size_t)b << 14) + ((size_t)(j0 + g) << 7) + (p << 3);
        #pragma unroll
        for (int s = 0; s < 8; ++s) bo[s] = v[s];
    }
}

// ---- K1: block=(b, t1-pair). x -> chirp -> FFT over t2 -> twiddle -> W1 ----
__global__ __launch_bounds__(256) void k1(const float* __restrict__ x,
                                          const float* __restrict__ rpm,
                                          __half2* __restrict__ w1) {
    __shared__ float2 Lw[16 * 137];
    __shared__ float2 Ls[128 * 17];
    __shared__ float2 chirpT[128];
    __shared__ float2 sWhi[128];
    __shared__ float2 sWlo[128];
    int tid = threadIdx.x;
    int g = tid >> 4, p = tid & 15;
    int bb = p >> 1, r = p & 1;
    int b = blockIdx.x >> 6;
    int t1_0 = (blockIdx.x & 63) << 1;

    load_tabs(sWhi, sWlo, tid);
    int n = compute_n(rpm[b]);
    int two_n = 2 * n;
    float inv_n = 1.0f / (float)n;
    if (tid < 128) {
        int t2 = tid >> 1, t1l = tid & 1;
        int t = t1_0 + t1l + (t2 << 7);
        int ph = (t * t) % two_n;
        float sn, cs; __sincosf(PI_F * (float)ph * inv_n, &sn, &cs);
        chirpT[tid] = make_float2(cs, -sn);     // exp(-i a_phase)
    }
    __syncthreads();
    // load x (line-complete 64B chunks), chirp-modulate, scatter to cols
    {
        const float2* xb2 = (const float2*)(x + ((size_t)b << 16));
        #pragma unroll
        for (int i = 0; i < 2; ++i) {
            int l = i * 256 + tid;              // l < 512
            int t2 = l >> 3, w = l & 7;
            int t1l = w >> 2, cp = w & 3;
            float2 xv = xb2[(size_t)(t1_0 + t1l + (t2 << 7)) * 4 + cp];
            float2 u = chirpT[t2 * 2 + t1l];
            int c = t1l * 8 + cp * 2;
            Lw[c * 137 + IDX(t2)]       = make_float2(xv.x * u.x, xv.x * u.y);
            Lw[(c + 1) * 137 + IDX(t2)] = make_float2(xv.y * u.x, xv.y * u.y);
        }
    }
    __syncthreads();
    // 16 column FFTs over t2 (col c = g = t1l*8+ch), twiddle chain, stage
    {
        float2 v[8];
        #pragma unroll
        for (int q = 0; q < 4; ++q) v[q] = Lw[g * 137 + IDX(p + 16*q)];
        difR<true>(v, Lw + g * 137, p, sWhi);
        int t1 = t1_0 + (g >> 3);
        int k2base = brev7(16*bb + r);
        float2 cur = wtab(sWhi, sWlo, t1 * k2base);
        float2 w8  = wtab(sWhi, sWlo, 8 * t1);
        #pragma unroll
        for (int e = 0; e < 8; ++e) {
            const int s = ((e & 1) << 2) | (e & 2) | ((e & 4) >> 2); // brev3(e)
            Ls[(16*bb + r + 2*s) * 17 + g] = cmul(v[s], cur);
            cur = cmul(cur, w8);
        }
    }
    __syncthreads();
    // copy out (fp16): per j a contiguous 64B chunk of W1[b][j][t1pair][ch]
    {
        __half2* wb = w1 + ((size_t)b << 17) + (t1_0 << 3);
        #pragma unroll
        for (int i = 0; i < 8; ++i) {
            int l = i * 256 + tid;              // l < 2048
            int j = l >> 4, w = l & 15;
            wb[((size_t)j << 10) + w] = __float22half2_rn(Ls[j * 17 + w]);
        }
    }
}

// ---- K2: block=(b, 4-j-slice). W1 -> FFT over t1 -> *Bhat -> iFFT -> S2 ----
__global__ __launch_bounds__(512) void k2(const __half2* __restrict__ w1,
                                          const float2* __restrict__ bhat,
                                          __half2* __restrict__ s2) {
    __shared__ float2 Lw[32 * 137];
    __shared__ float2 Ls[128 * 33];
    __shared__ float2 sWhi[128];
    __shared__ float2 sWlo[128];
    int tid = threadIdx.x;
    int g = tid >> 4, p = tid & 15;             // g in [0,32)
    int b = blockIdx.x >> 5;
    int j0 = (blockIdx.x & 31) << 2;

    load_tabs(sWhi, sWlo, tid);
    __syncthreads();
    // load 32 rows (jl,ch) x 128 t1: contiguous 16 KB
    {
        const __half2* rb = w1 + ((size_t)b << 17) + ((size_t)j0 << 10);
        #pragma unroll
        for (int i = 0; i < 8; ++i) {
            int l = i * 512 + tid;              // l < 4096
            int jl = l >> 10, t1 = (l >> 3) & 127, ch = l & 7;
            Lw[(jl * 8 + ch) * 137 + IDX(t1)] = __half22float2(rb[l]);
        }
    }
    __syncthreads();
    {
        float2* Lf = Lw + g * 137;
        float2 v[8];
        #pragma unroll
        for (int q = 0; q < 8; ++q) v[q] = Lf[IDX(p + 16*q)];
        difR<false>(v, Lf, p, sWhi);
        int j = j0 + (g >> 3);
        const float2* bhp = bhat + ((size_t)b << 14) + (j << 7) + (p << 3);
        #pragma unroll
        for (int s = 0; s < 8; ++s) v[s] = cmul(v[s], bhp[s]);
        ditR<false>(v, Lf, p, sWhi);
        int k2v = brev7(j);
        float2 cur = wtab(sWhi, sWlo, k2v * p);
        float2 w16 = wtab(sWhi, sWlo, 16 * k2v);
        #pragma unroll
        for (int q = 0; q < 8; ++q) {
            // * exp(+2pi i k2 t1/M) * (1/M)  (scale folded here for fp16 range)
            float2 tw = make_float2(cur.x * (1.0f/16384.0f), -cur.y * (1.0f/16384.0f));
            Ls[(p + 16*q) * 33 + g] = cmul(v[q], tw);
            cur = cmul(cur, w16);
        }
    }
    __syncthreads();
    // copy out (fp16): per t1 a contiguous 128B chunk of S2[b][t1][jslice][ch]
    {
        __half2* sb = s2 + ((size_t)b << 17) + (j0 << 3);
        #pragma unroll
        for (int i = 0; i < 8; ++i) {
            int l = i * 512 + tid;              // l < 4096
            int t1 = l >> 5, w = l & 31;
            sb[((size_t)t1 << 10) + w] = __float22half2_rn(Ls[t1 * 33 + w]);
        }
    }
}

// ---- K3: block=(b, t1-pair). S2 -> iFFT over j -> |.| -> out ----
__global__ __launch_bounds__(256) void k3(const __half2* __restrict__ s2,
                                          float* __restrict__ outF) {
    __shared__ float2 Lw[16 * 137];
    __shared__ float Lsf[64 * 20 + 16];
    __shared__ float2 sWhi[128];
    __shared__ float2 sWlo[128];
    int tid = threadIdx.x;
    int g = tid >> 4, p = tid & 15;
    int bb = p >> 1, r = p & 1;
    int b = blockIdx.x >> 6;
    int t1_0 = (blockIdx.x & 63) << 1;

    load_tabs(sWhi, sWlo, tid);
    __syncthreads();
    // load 2 t1 x 128 j x 8 ch: contiguous 8 KB
    {
        const __half2* rb = s2 + ((size_t)b << 17) + ((size_t)t1_0 << 10);
        #pragma unroll
        for (int i = 0; i < 8; ++i) {
            int l = i * 256 + tid;              // l < 2048
            int t1l = l >> 10, j = (l >> 3) & 127, ch = l & 7;
            Lw[(t1l * 8 + ch) * 137 + IDX(j)] = __half22float2(rb[l]);
        }
    }
    __syncthreads();
    {
        float2* Lf = Lw + g * 137;
        float2 v[8];
        #pragma unroll
        for (int s = 0; s < 8; ++s) v[s] = Lf[IDX(16*bb + r + 2*s)];
        ditR<true>(v, Lf, p, sWhi);
        // v[q] = z[m = t1 + 128*(p+16q)], q<4; 1/M already applied in k2
        #pragma unroll
        for (int q = 0; q < 4; ++q) {
            float2 z = v[q];
            Lsf[(p + 16*q) * 20 + g] = sqrtf(z.x*z.x + z.y*z.y);
        }
    }
    __syncthreads();
    // copy out: per t2 a line-complete 64B chunk of out[b][m][ch]
    {
        float* ob = outF + ((size_t)b << 16) + (t1_0 << 3);
        #pragma unroll
        for (int i = 0; i < 4; ++i) {
            int l = i * 256 + tid;              // l < 1024
            int t2 = l >> 4, w = l & 15;
            ob[((size_t)t2 << 10) + w] = Lsf[t2 * 20 + w];
        }
    }
}

// ---------------- launch ----------------
extern "C" void kernel_launch(void* const* d_in, const int* in_sizes, int n_in,
                              void* d_out, int out_size, void* d_ws, size_t ws_size,
                              hipStream_t stream) {
    const float* x   = (const float*)d_in[0];
    const float* rpm = (const float*)d_in[1];
    float* outF = (float*)d_out;
    __half2* w1  = (__half2*)d_ws;                               // 32 MiB
    __half2* s2  = w1 + (size_t)Bn * 131072;                     // 32 MiB
    float2* w1c  = (float2*)(s2 + (size_t)Bn * 131072);          // 8 MiB (chirp temp)
    float2* bhat = (float2*)d_out;                               // 8 MiB, dead before k3

    bhat_p1<<<Bn * 8, 256, 0, stream>>>(rpm, w1c);
    bhat_p2<<<Bn * 8, 256, 0, stream>>>(w1c, bhat);
    k1<<<Bn * 64, 256, 0, stream>>>(x, rpm, w1);
    k2<<<Bn * 32, 512, 0, stream>>>(w1, bhat, s2);
    k3<<<Bn * 64, 256, 0, stream>>>(s2, outF);
}

// Round 11
// 76.281 us; speedup vs baseline: 3.5536x; 1.0984x over previous
//
#include <hip/hip_runtime.h>
#include <hip/hip_fp16.h>
#include <math.h>

// EngineOrderFFT via batched Bluestein. |X| = |conv[:, :K]|. M=16384 as a
// 128x128 four-step, 4 kernels, line-complete global I/O (R8-proven),
// fp16 intermediates (R9-proven).
// R10: (a) output-staging LDS aliased into the dead input buffer in every
// kernel (+1 barrier) -- k1 38->21 KB, k2 71->41 KB, k3 25->20 KB, big
// occupancy gains; (b) bhat_p2 fused into k2: wave 0 computes the block's
// own 4 Bhat row-FFTs from W1c into a small conflict-free LDS scratch while
// the other waves run the main forward FFT.
//   W1[b][j][t1][ch] (half2), S2[b][t1][j][ch] (half2, 1/M pre-folded)
//   W1c[b][j][t1] (float2, chirp spectrum after pass 1)

static constexpr int Bn = 64;

#define PI_F 3.14159265358979323846f
#define TWO_PI_F 6.28318530717958647692f
#define R2_F 0.70710678118654752f

__device__ __forceinline__ int compute_n(float rpm) {
    // ref: pad = floor((40*60/rpm - 1)*8192) in f32; n = 8192 + pad
    return 8192 + (int)floorf((2400.0f / rpm - 1.0f) * 8192.0f);
}
__device__ __forceinline__ float2 cmul(float2 a, float2 b) {
    return make_float2(a.x*b.x - a.y*b.y, a.x*b.y + a.y*b.x);
}
__device__ __forceinline__ float2 cadd(float2 a, float2 b){ return make_float2(a.x+b.x, a.y+b.y); }
__device__ __forceinline__ float2 csub(float2 a, float2 b){ return make_float2(a.x-b.x, a.y-b.y); }
__device__ __forceinline__ float2 shflx1(float2 v) {
    return make_float2(__shfl_xor(v.x, 1, 64), __shfl_xor(v.y, 1, 64));
}
__device__ __forceinline__ int brev7(int x) { return (int)(__brev((unsigned)x) >> 25); }

#define BF(lo,hi,tw) { float2 _d = csub(lo,hi); lo = cadd(lo,hi); hi = cmul(_d, tw); }
#define BT(lo,hi,tw) { float2 _b = cmul(hi,tw); hi = csub(lo,_b); lo = cadd(lo,_b); }
#define SELC(r,c0,s0,c1,s1) ((r) ? make_float2(c1,s1) : make_float2(c0,s0))
#define IDX(u) ((u) + ((u) >> 4))          // row-local pad (R2/R3-proven)

// W_M^{-m}: Whi[m]=exp(-i*pi*m/64), Wlo[m]=exp(-i*pi*m/8192)
__device__ __forceinline__ float2 wtab(const float2* Whi, const float2* Wlo, int m) {
    return cmul(Whi[m >> 7], Wlo[m & 127]);
}

// ====== row-local cores. Lf = per-FFT scratch region (>=136 f2) ======
// HZ: inputs v[4..7] are implicit zeros (not loaded).
template<bool HZ>
__device__ __forceinline__ void difR(float2 v[8], float2* Lf, int p,
                                     const float2* sWhi) {
    float2 w1 = sWhi[p];                        // exp(-i*pi*p/64)
    float2 w2 = cmul(w1, w1);
    float2 w4 = cmul(w2, w2);
    float2 w1b = cmul(w1, make_float2(R2_F,-R2_F));
    float2 w1c = make_float2(w1.y, -w1.x);
    float2 w1d = cmul(w1, make_float2(-R2_F,-R2_F));
    float2 w2i = make_float2(w2.y, -w2.x);
    if (HZ) {
        v[4] = cmul(v[0], w1);
        v[5] = cmul(v[1], w1b);
        v[6] = cmul(v[2], w1c);
        v[7] = cmul(v[3], w1d);
    } else {
        BF(v[0],v[4], w1);
        BF(v[1],v[5], w1b);
        BF(v[2],v[6], w1c);
        BF(v[3],v[7], w1d);
    }
    BF(v[0],v[2], w2);  BF(v[1],v[3], w2i);
    BF(v[4],v[6], w2);  BF(v[5],v[7], w2i);
    BF(v[0],v[1], w4);  BF(v[2],v[3], w4);
    BF(v[4],v[5], w4);  BF(v[6],v[7], w4);
    #pragma unroll
    for (int q = 0; q < 8; ++q) Lf[IDX(p + 16*q)] = v[q];
    int bb = p >> 1, r = p & 1;
    #pragma unroll
    for (int s = 0; s < 8; ++s) v[s] = Lf[IDX(16*bb + r + 2*s)];
    BF(v[0],v[4], SELC(r, 1.f,0.f,                    0.92387953f,-0.38268343f));
    BF(v[1],v[5], SELC(r, 0.70710678f,-0.70710678f,   0.38268343f,-0.92387953f));
    BF(v[2],v[6], SELC(r, 0.f,-1.f,                  -0.38268343f,-0.92387953f));
    BF(v[3],v[7], SELC(r, -0.70710678f,-0.70710678f, -0.92387953f,-0.38268343f));
    BF(v[0],v[2], SELC(r, 1.f,0.f,  0.70710678f,-0.70710678f));
    BF(v[1],v[3], SELC(r, 0.f,-1.f, -0.70710678f,-0.70710678f));
    BF(v[4],v[6], SELC(r, 1.f,0.f,  0.70710678f,-0.70710678f));
    BF(v[5],v[7], SELC(r, 0.f,-1.f, -0.70710678f,-0.70710678f));
    #pragma unroll
    for (int s = 0; s < 8; s += 2) {
        float2 d = csub(v[s], v[s+1]);
        v[s] = cadd(v[s], v[s+1]);
        v[s+1] = r ? make_float2(d.y, -d.x) : d;
    }
    #pragma unroll
    for (int s = 0; s < 8; ++s) {
        float2 o = shflx1(v[s]);
        v[s] = r ? csub(o, v[s]) : cadd(v[s], o);
    }
}

// HOUT: only lo outputs v[0..3] of the final stage are produced.
template<bool HOUT>
__device__ __forceinline__ void ditR(float2 v[8], float2* Lf, int p,
                                     const float2* sWhi) {
    int bb = p >> 1, r = p & 1;
    #pragma unroll
    for (int s = 0; s < 8; ++s) {
        float2 o = shflx1(v[s]);
        v[s] = r ? csub(o, v[s]) : cadd(v[s], o);
    }
    #pragma unroll
    for (int s = 0; s < 8; s += 2) {
        float2 bq = v[s+1];
        if (r) bq = make_float2(-bq.y, bq.x);
        v[s+1] = csub(v[s], bq);
        v[s] = cadd(v[s], bq);
    }
    BT(v[0],v[2], SELC(r, 1.f,0.f,  0.70710678f,0.70710678f));
    BT(v[1],v[3], SELC(r, 0.f,1.f, -0.70710678f,0.70710678f));
    BT(v[4],v[6], SELC(r, 1.f,0.f,  0.70710678f,0.70710678f));
    BT(v[5],v[7], SELC(r, 0.f,1.f, -0.70710678f,0.70710678f));
    BT(v[0],v[4], SELC(r, 1.f,0.f,                   0.92387953f,0.38268343f));
    BT(v[1],v[5], SELC(r, 0.70710678f,0.70710678f,   0.38268343f,0.92387953f));
    BT(v[2],v[6], SELC(r, 0.f,1.f,                  -0.38268343f,0.92387953f));
    BT(v[3],v[7], SELC(r, -0.70710678f,0.70710678f, -0.92387953f,0.38268343f));
    #pragma unroll
    for (int s = 0; s < 8; ++s) Lf[IDX(16*bb + r + 2*s)] = v[s];
    #pragma unroll
    for (int q = 0; q < 8; ++q) v[q] = Lf[IDX(p + 16*q)];
    float2 w1 = make_float2(sWhi[p].x, -sWhi[p].y);   // exp(+i*pi*p/64)
    float2 w2 = cmul(w1, w1);
    float2 w4 = cmul(w2, w2);
    float2 w2j = make_float2(-w2.y, w2.x);
    float2 w1b = cmul(w1, make_float2(R2_F, R2_F));
    float2 w1c = make_float2(-w1.y, w1.x);
    float2 w1d = cmul(w1, make_float2(-R2_F, R2_F));
    BT(v[0],v[1], w4); BT(v[2],v[3], w4);
    BT(v[4],v[5], w4); BT(v[6],v[7], w4);
    BT(v[0],v[2], w2);  BT(v[1],v[3], w2j);
    BT(v[4],v[6], w2);  BT(v[5],v[7], w2j);
    if (HOUT) {
        v[0] = cadd(v[0], cmul(v[4], w1));
        v[1] = cadd(v[1], cmul(v[5], w1b));
        v[2] = cadd(v[2], cmul(v[6], w1c));
        v[3] = cadd(v[3], cmul(v[7], w1d));
    } else {
        BT(v[0],v[4], w1);
        BT(v[1],v[5], w1b);
        BT(v[2],v[6], w1c);
        BT(v[3],v[7], w1d);
    }
}

__device__ __forceinline__ void load_tabs(float2* sWhi, float2* sWlo, int tid) {
    if (tid < 128) {
        float sn, cs; __sincosf(PI_F * (float)tid * (1.0f/64.0f), &sn, &cs);
        sWhi[tid] = make_float2(cs, -sn);
    } else if (tid < 256) {
        int m = tid - 128;
        float sn, cs; __sincosf(PI_F * (float)m * (1.0f/8192.0f), &sn, &cs);
        sWlo[m] = make_float2(cs, -sn);
    }
}

// ---- bhat p1: block=(b, 16-t1-group). chirp -> FFT over t2 -> twiddle -> W1c
// Output staging aliased into Lw (barrier after FFT).
__global__ __launch_bounds__(256) void bhat_p1(const float* __restrict__ rpm,
                                               float2* __restrict__ w1c) {
    __shared__ float2 Lw[16 * 137];            // also aliased as Ls[128*17]
    __shared__ float2 sWhi[128];
    __shared__ float2 sWlo[128];
    int tid = threadIdx.x;
    int g = tid >> 4, p = tid & 15;
    int bb = p >> 1, r = p & 1;
    int b = blockIdx.x >> 3;
    int t1_0 = (blockIdx.x & 7) << 4;

    load_tabs(sWhi, sWlo, tid);
    int n = compute_n(rpm[b]);
    int two_n = 2 * n;
    float inv_n = 1.0f / (float)n;
    #pragma unroll
    for (int i = 0; i < 8; ++i) {
        int l = i * 256 + tid;
        int t2 = l >> 4, c = l & 15;
        int t = (t1_0 + c) + (t2 << 7);
        int mm = min(t, 16384 - t);
        int ph = (mm * mm) % two_n;
        float sn, cs; __sincosf(PI_F * (float)ph * inv_n, &sn, &cs);
        Lw[c * 137 + IDX(t2)] = make_float2(cs, sn);   // exp(+i b_phase)
    }
    __syncthreads();
    float2 v[8];
    #pragma unroll
    for (int q = 0; q < 8; ++q) v[q] = Lw[g * 137 + IDX(p + 16*q)];
    difR<false>(v, Lw + g * 137, p, sWhi);
    __syncthreads();                            // Lw dead -> alias as Ls
    {
        int t1 = t1_0 + g;
        int k2base = brev7(16*bb + r);
        float2 cur = wtab(sWhi, sWlo, t1 * k2base);
        float2 w8  = wtab(sWhi, sWlo, 8 * t1);
        #pragma unroll
        for (int e = 0; e < 8; ++e) {
            const int s = ((e & 1) << 2) | (e & 2) | ((e & 4) >> 2); // brev3(e)
            Lw[(16*bb + r + 2*s) * 17 + g] = cmul(v[s], cur);
            cur = cmul(cur, w8);
        }
    }
    __syncthreads();
    {
        float2* wb = w1c + ((size_t)b << 14) + t1_0;
        #pragma unroll
        for (int i = 0; i < 8; ++i) {
            int l = i * 256 + tid;              // l < 2048
            int j = l >> 4, w = l & 15;
            wb[(j << 7) + w] = Lw[j * 17 + w];
        }
    }
}

// ---- K1: block=(b, t1-pair). x -> chirp -> FFT over t2 -> twiddle -> W1 ----
__global__ __launch_bounds__(256) void k1(const float* __restrict__ x,
                                          const float* __restrict__ rpm,
                                          __half2* __restrict__ w1) {
    __shared__ float2 Lw[16 * 137];            // also aliased as Ls[128*17]
    __shared__ float2 chirpT[128];
    __shared__ float2 sWhi[128];
    __shared__ float2 sWlo[128];
    int tid = threadIdx.x;
    int g = tid >> 4, p = tid & 15;
    int bb = p >> 1, r = p & 1;
    int b = blockIdx.x >> 6;
    int t1_0 = (blockIdx.x & 63) << 1;

    load_tabs(sWhi, sWlo, tid);
    int n = compute_n(rpm[b]);
    int two_n = 2 * n;
    float inv_n = 1.0f / (float)n;
    if (tid < 128) {
        int t2 = tid >> 1, t1l = tid & 1;
        int t = t1_0 + t1l + (t2 << 7);
        int ph = (t * t) % two_n;
        float sn, cs; __sincosf(PI_F * (float)ph * inv_n, &sn, &cs);
        chirpT[tid] = make_float2(cs, -sn);     // exp(-i a_phase)
    }
    __syncthreads();
    {
        const float2* xb2 = (const float2*)(x + ((size_t)b << 16));
        #pragma unroll
        for (int i = 0; i < 2; ++i) {
            int l = i * 256 + tid;              // l < 512
            int t2 = l >> 3, w = l & 7;
            int t1l = w >> 2, cp = w & 3;
            float2 xv = xb2[(size_t)(t1_0 + t1l + (t2 << 7)) * 4 + cp];
            float2 u = chirpT[t2 * 2 + t1l];
            int c = t1l * 8 + cp * 2;
            Lw[c * 137 + IDX(t2)]       = make_float2(xv.x * u.x, xv.x * u.y);
            Lw[(c + 1) * 137 + IDX(t2)] = make_float2(xv.y * u.x, xv.y * u.y);
        }
    }
    __syncthreads();
    float2 v[8];
    #pragma unroll
    for (int q = 0; q < 4; ++q) v[q] = Lw[g * 137 + IDX(p + 16*q)];
    difR<true>(v, Lw + g * 137, p, sWhi);
    __syncthreads();                            // Lw dead -> alias as Ls
    {
        int t1 = t1_0 + (g >> 3);
        int k2base = brev7(16*bb + r);
        float2 cur = wtab(sWhi, sWlo, t1 * k2base);
        float2 w8  = wtab(sWhi, sWlo, 8 * t1);
        #pragma unroll
        for (int e = 0; e < 8; ++e) {
            const int s = ((e & 1) << 2) | (e & 2) | ((e & 4) >> 2); // brev3(e)
            Lw[(16*bb + r + 2*s) * 17 + g] = cmul(v[s], cur);
            cur = cmul(cur, w8);
        }
    }
    __syncthreads();
    {
        __half2* wb = w1 + ((size_t)b << 17) + (t1_0 << 3);
        #pragma unroll
        for (int i = 0; i < 8; ++i) {
            int l = i * 256 + tid;              // l < 2048
            int j = l >> 4, w = l & 15;
            wb[((size_t)j << 10) + w] = __float22half2_rn(Lw[j * 17 + w]);
        }
    }
}

// ---- K2: block=(b, 4-j-slice). W1 -> FFT over t1 -> *Bhat(computed in-block
// from W1c by wave 0) -> iFFT -> twiddle*(1/M) -> S2 ----
__global__ __launch_bounds__(512) void k2(const __half2* __restrict__ w1,
                                          const float2* __restrict__ w1c,
                                          __half2* __restrict__ s2) {
    __shared__ float2 Lw[32 * 137];            // also aliased as Ls[128*33]
    __shared__ float2 Wsc[4 * 137];            // Bhat scratch + result [s*17+p]
    __shared__ float2 sWhi[128];
    __shared__ float2 sWlo[128];
    int tid = threadIdx.x;
    int g = tid >> 4, p = tid & 15;             // g in [0,32)
    int b = blockIdx.x >> 5;
    int j0 = (blockIdx.x & 31) << 2;

    load_tabs(sWhi, sWlo, tid);
    // Bhat input prefetch (wave 0: groups 0..3 <-> jl 0..3), overlaps staging
    float2 vb[8];
    if (g < 4) {
        const float2* wc = w1c + ((size_t)b << 14) + ((size_t)(j0 + g) << 7);
        #pragma unroll
        for (int q = 0; q < 8; ++q) vb[q] = wc[p + 16*q];
    }
    // stage W1 (fp16 -> f32): 32 rows (jl,ch) x 128 t1, contiguous 16 KB
    {
        const __half2* rb = w1 + ((size_t)b << 17) + ((size_t)j0 << 10);
        #pragma unroll
        for (int i = 0; i < 8; ++i) {
            int l = i * 512 + tid;              // l < 4096
            int jl = l >> 10, t1 = (l >> 3) & 127, ch = l & 7;
            Lw[(jl * 8 + ch) * 137 + IDX(t1)] = __half22float2(rb[l]);
        }
    }
    __syncthreads();
    // wave 0: 4 Bhat row-FFTs into Wsc (result layout [jl][s*17+p], cf-free)
    if (g < 4) {
        difR<false>(vb, Wsc + g * 137, p, sWhi);
        #pragma unroll
        for (int s = 0; s < 8; ++s) Wsc[g * 137 + s * 17 + p] = vb[s];
    }
    // all: main forward FFT over t1
    float2* Lf = Lw + g * 137;
    float2 v[8];
    #pragma unroll
    for (int q = 0; q < 8; ++q) v[q] = Lf[IDX(p + 16*q)];
    difR<false>(v, Lf, p, sWhi);
    __syncthreads();                            // Wsc published
    {
        int jl = g >> 3;
        #pragma unroll
        for (int s = 0; s < 8; ++s) v[s] = cmul(v[s], Wsc[jl * 137 + s * 17 + p]);
    }
    ditR<false>(v, Lf, p, sWhi);
    int j = j0 + (g >> 3);
    int k2v = brev7(j);
    __syncthreads();                            // all Lf scratch done -> alias Ls
    {
        float2 cur = wtab(sWhi, sWlo, k2v * p);
        float2 w16 = wtab(sWhi, sWlo, 16 * k2v);
        #pragma unroll
        for (int q = 0; q < 8; ++q) {
            // * exp(+2pi i k2 t1/M) * (1/M)  (scale folded for fp16 range)
            float2 tw = make_float2(cur.x * (1.0f/16384.0f), -cur.y * (1.0f/16384.0f));
            Lw[(p + 16*q) * 33 + g] = cmul(v[q], tw);
            cur = cmul(cur, w16);
        }
    }
    __syncthreads();
    {
        __half2* sb = s2 + ((size_t)b << 17) + (j0 << 3);
        #pragma unroll
        for (int i = 0; i < 8; ++i) {
            int l = i * 512 + tid;              // l < 4096
            int t1 = l >> 5, w = l & 31;
            sb[((size_t)t1 << 10) + w] = __float22half2_rn(Lw[t1 * 33 + w]);
        }
    }
}

// ---- K3: block=(b, t1-pair). S2 -> iFFT over j -> |.| -> out ----
__global__ __launch_bounds__(256) void k3(const __half2* __restrict__ s2,
                                          float* __restrict__ outF) {
    __shared__ float2 Lw[16 * 137];            // also aliased as Lsf (floats)
    __shared__ float2 sWhi[128];
    __shared__ float2 sWlo[128];
    int tid = threadIdx.x;
    int g = tid >> 4, p = tid & 15;
    int bb = p >> 1, r = p & 1;
    int b = blockIdx.x >> 6;
    int t1_0 = (blockIdx.x & 63) << 1;

    load_tabs(sWhi, sWlo, tid);
    {
        const __half2* rb = s2 + ((size_t)b << 17) + ((size_t)t1_0 << 10);
        #pragma unroll
        for (int i = 0; i < 8; ++i) {
            int l = i * 256 + tid;              // l < 2048 (8 KB contiguous)
            int t1l = l >> 10, j = (l >> 3) & 127, ch = l & 7;
            Lw[(t1l * 8 + ch) * 137 + IDX(j)] = __half22float2(rb[l]);
        }
    }
    __syncthreads();
    float2 v[8];
    {
        float2* Lf = Lw + g * 137;
        #pragma unroll
        for (int s = 0; s < 8; ++s) v[s] = Lf[IDX(16*bb + r + 2*s)];
        ditR<true>(v, Lf, p, sWhi);
    }
    __syncthreads();                            // Lw dead -> alias as float Lsf
    float* Lsf = (float*)Lw;
    #pragma unroll
    for (int q = 0; q < 4; ++q) {
        // v[q] = z[m = t1 + 128*(p+16q)], q<4 (1/M applied in k2)
        float2 z = v[q];
        Lsf[(p + 16*q) * 20 + g] = sqrtf(z.x*z.x + z.y*z.y);
    }
    __syncthreads();
    {
        float* ob = outF + ((size_t)b << 16) + (t1_0 << 3);
        #pragma unroll
        for (int i = 0; i < 4; ++i) {
            int l = i * 256 + tid;              // l < 1024
            int t2 = l >> 4, w = l & 15;
            ob[((size_t)t2 << 10) + w] = Lsf[t2 * 20 + w];
        }
    }
}

// ---------------- launch ----------------
extern "C" void kernel_launch(void* const* d_in, const int* in_sizes, int n_in,
                              void* d_out, int out_size, void* d_ws, size_t ws_size,
                              hipStream_t stream) {
    const float* x   = (const float*)d_in[0];
    const float* rpm = (const float*)d_in[1];
    float* outF = (float*)d_out;
    __half2* w1  = (__half2*)d_ws;                               // 32 MiB
    __half2* s2  = w1 + (size_t)Bn * 131072;                     // 32 MiB
    float2* w1c  = (float2*)(s2 + (size_t)Bn * 131072);          // 8 MiB

    bhat_p1<<<Bn * 8, 256, 0, stream>>>(rpm, w1c);
    k1<<<Bn * 64, 256, 0, stream>>>(x, rpm, w1);
    k2<<<Bn * 32, 512, 0, stream>>>(w1, w1c, s2);
    k3<<<Bn * 64, 256, 0, stream>>>(s2, outF);
}

// Round 13
// 70.478 us; speedup vs baseline: 3.8462x; 1.0823x over previous
//
#include <hip/hip_runtime.h>
#include <hip/hip_fp16.h>
#include <math.h>

// EngineOrderFFT via batched Bluestein. |X| = |conv[:, :K]|. M=16384 as a
// 128x128 four-step, 3 kernel launches, line-complete global I/O (R8),
// fp16 intermediates (R9), LDS aliasing + in-block Bhat (R10).
// R12 = R11 fixed: (a) ALL global I/O vectorized to 16 B/lane (float4 of
// 4 half2, bit-cast); (b) bhat_p1 merged into the k1 launch (grid-split).
// R11's bug: k1 x-load loop ran 512 elements (t2 to 127) instead of 256
// (t2 < 64, HZ trim) -> OOB read of x -> GPU fault.
//   W1[b][j][t1][ch] (half2), S2[b][t1][j][ch] (half2, 1/M pre-folded)
//   W1c[b][j][t1] (float2, chirp spectrum after pass 1)

static constexpr int Bn = 64;

#define PI_F 3.14159265358979323846f
#define TWO_PI_F 6.28318530717958647692f
#define R2_F 0.70710678118654752f

__device__ __forceinline__ int compute_n(float rpm) {
    // ref: pad = floor((40*60/rpm - 1)*8192) in f32; n = 8192 + pad
    return 8192 + (int)floorf((2400.0f / rpm - 1.0f) * 8192.0f);
}
__device__ __forceinline__ float2 cmul(float2 a, float2 b) {
    return make_float2(a.x*b.x - a.y*b.y, a.x*b.y + a.y*b.x);
}
__device__ __forceinline__ float2 cadd(float2 a, float2 b){ return make_float2(a.x+b.x, a.y+b.y); }
__device__ __forceinline__ float2 csub(float2 a, float2 b){ return make_float2(a.x-b.x, a.y-b.y); }
__device__ __forceinline__ float2 shflx1(float2 v) {
    return make_float2(__shfl_xor(v.x, 1, 64), __shfl_xor(v.y, 1, 64));
}
__device__ __forceinline__ int brev7(int x) { return (int)(__brev((unsigned)x) >> 25); }

// fp16 pack/unpack via 32-bit bit-cast (keeps global I/O in float4 lanes)
__device__ __forceinline__ float f2h_bits(float2 a) {
    union { __half2 h; float f; } u;
    u.h = __float22half2_rn(a);
    return u.f;
}
__device__ __forceinline__ float2 h2f_bits(float w) {
    union { float f; __half2 h; } u;
    u.f = w;
    return __half22float2(u.h);
}

#define BF(lo,hi,tw) { float2 _d = csub(lo,hi); lo = cadd(lo,hi); hi = cmul(_d, tw); }
#define BT(lo,hi,tw) { float2 _b = cmul(hi,tw); hi = csub(lo,_b); lo = cadd(lo,_b); }
#define SELC(r,c0,s0,c1,s1) ((r) ? make_float2(c1,s1) : make_float2(c0,s0))
#define IDX(u) ((u) + ((u) >> 4))          // row-local pad (R2/R3-proven)

// W_M^{-m}: Whi[m]=exp(-i*pi*m/64), Wlo[m]=exp(-i*pi*m/8192)
__device__ __forceinline__ float2 wtab(const float2* Whi, const float2* Wlo, int m) {
    return cmul(Whi[m >> 7], Wlo[m & 127]);
}

// ====== row-local cores. Lf = per-FFT scratch region (>=136 f2) ======
// HZ: inputs v[4..7] are implicit zeros (not loaded).
template<bool HZ>
__device__ __forceinline__ void difR(float2 v[8], float2* Lf, int p,
                                     const float2* sWhi) {
    float2 w1 = sWhi[p];                        // exp(-i*pi*p/64)
    float2 w2 = cmul(w1, w1);
    float2 w4 = cmul(w2, w2);
    float2 w1b = cmul(w1, make_float2(R2_F,-R2_F));
    float2 w1c = make_float2(w1.y, -w1.x);
    float2 w1d = cmul(w1, make_float2(-R2_F,-R2_F));
    float2 w2i = make_float2(w2.y, -w2.x);
    if (HZ) {
        v[4] = cmul(v[0], w1);
        v[5] = cmul(v[1], w1b);
        v[6] = cmul(v[2], w1c);
        v[7] = cmul(v[3], w1d);
    } else {
        BF(v[0],v[4], w1);
        BF(v[1],v[5], w1b);
        BF(v[2],v[6], w1c);
        BF(v[3],v[7], w1d);
    }
    BF(v[0],v[2], w2);  BF(v[1],v[3], w2i);
    BF(v[4],v[6], w2);  BF(v[5],v[7], w2i);
    BF(v[0],v[1], w4);  BF(v[2],v[3], w4);
    BF(v[4],v[5], w4);  BF(v[6],v[7], w4);
    #pragma unroll
    for (int q = 0; q < 8; ++q) Lf[IDX(p + 16*q)] = v[q];
    int bb = p >> 1, r = p & 1;
    #pragma unroll
    for (int s = 0; s < 8; ++s) v[s] = Lf[IDX(16*bb + r + 2*s)];
    BF(v[0],v[4], SELC(r, 1.f,0.f,                    0.92387953f,-0.38268343f));
    BF(v[1],v[5], SELC(r, 0.70710678f,-0.70710678f,   0.38268343f,-0.92387953f));
    BF(v[2],v[6], SELC(r, 0.f,-1.f,                  -0.38268343f,-0.92387953f));
    BF(v[3],v[7], SELC(r, -0.70710678f,-0.70710678f, -0.92387953f,-0.38268343f));
    BF(v[0],v[2], SELC(r, 1.f,0.f,  0.70710678f,-0.70710678f));
    BF(v[1],v[3], SELC(r, 0.f,-1.f, -0.70710678f,-0.70710678f));
    BF(v[4],v[6], SELC(r, 1.f,0.f,  0.70710678f,-0.70710678f));
    BF(v[5],v[7], SELC(r, 0.f,-1.f, -0.70710678f,-0.70710678f));
    #pragma unroll
    for (int s = 0; s < 8; s += 2) {
        float2 d = csub(v[s], v[s+1]);
        v[s] = cadd(v[s], v[s+1]);
        v[s+1] = r ? make_float2(d.y, -d.x) : d;
    }
    #pragma unroll
    for (int s = 0; s < 8; ++s) {
        float2 o = shflx1(v[s]);
        v[s] = r ? csub(o, v[s]) : cadd(v[s], o);
    }
}

// HOUT: only lo outputs v[0..3] of the final stage are produced.
template<bool HOUT>
__device__ __forceinline__ void ditR(float2 v[8], float2* Lf, int p,
                                     const float2* sWhi) {
    int bb = p >> 1, r = p & 1;
    #pragma unroll
    for (int s = 0; s < 8; ++s) {
        float2 o = shflx1(v[s]);
        v[s] = r ? csub(o, v[s]) : cadd(v[s], o);
    }
    #pragma unroll
    for (int s = 0; s < 8; s += 2) {
        float2 bq = v[s+1];
        if (r) bq = make_float2(-bq.y, bq.x);
        v[s+1] = csub(v[s], bq);
        v[s] = cadd(v[s], bq);
    }
    BT(v[0],v[2], SELC(r, 1.f,0.f,  0.70710678f,0.70710678f));
    BT(v[1],v[3], SELC(r, 0.f,1.f, -0.70710678f,0.70710678f));
    BT(v[4],v[6], SELC(r, 1.f,0.f,  0.70710678f,0.70710678f));
    BT(v[5],v[7], SELC(r, 0.f,1.f, -0.70710678f,0.70710678f));
    BT(v[0],v[4], SELC(r, 1.f,0.f,                   0.92387953f,0.38268343f));
    BT(v[1],v[5], SELC(r, 0.70710678f,0.70710678f,   0.38268343f,0.92387953f));
    BT(v[2],v[6], SELC(r, 0.f,1.f,                  -0.38268343f,0.92387953f));
    BT(v[3],v[7], SELC(r, -0.70710678f,0.70710678f, -0.92387953f,0.38268343f));
    #pragma unroll
    for (int s = 0; s < 8; ++s) Lf[IDX(16*bb + r + 2*s)] = v[s];
    #pragma unroll
    for (int q = 0; q < 8; ++q) v[q] = Lf[IDX(p + 16*q)];
    float2 w1 = make_float2(sWhi[p].x, -sWhi[p].y);   // exp(+i*pi*p/64)
    float2 w2 = cmul(w1, w1);
    float2 w4 = cmul(w2, w2);
    float2 w2j = make_float2(-w2.y, w2.x);
    float2 w1b = cmul(w1, make_float2(R2_F, R2_F));
    float2 w1c = make_float2(-w1.y, w1.x);
    float2 w1d = cmul(w1, make_float2(-R2_F, R2_F));
    BT(v[0],v[1], w4); BT(v[2],v[3], w4);
    BT(v[4],v[5], w4); BT(v[6],v[7], w4);
    BT(v[0],v[2], w2);  BT(v[1],v[3], w2j);
    BT(v[4],v[6], w2);  BT(v[5],v[7], w2j);
    if (HOUT) {
        v[0] = cadd(v[0], cmul(v[4], w1));
        v[1] = cadd(v[1], cmul(v[5], w1b));
        v[2] = cadd(v[2], cmul(v[6], w1c));
        v[3] = cadd(v[3], cmul(v[7], w1d));
    } else {
        BT(v[0],v[4], w1);
        BT(v[1],v[5], w1b);
        BT(v[2],v[6], w1c);
        BT(v[3],v[7], w1d);
    }
}

__device__ __forceinline__ void load_tabs(float2* sWhi, float2* sWlo, int tid) {
    if (tid < 128) {
        float sn, cs; __sincosf(PI_F * (float)tid * (1.0f/64.0f), &sn, &cs);
        sWhi[tid] = make_float2(cs, -sn);
    } else if (tid < 256) {
        int m = tid - 128;
        float sn, cs; __sincosf(PI_F * (float)m * (1.0f/8192.0f), &sn, &cs);
        sWlo[m] = make_float2(cs, -sn);
    }
}

// ---- K1B: merged launch. Blocks [0, Bn*8): bhat pass 1 (chirp -> FFT over
// t2 -> twiddle -> W1c). Blocks [Bn*8, ...): main K1 (x -> chirp -> FFT over
// t2 -> twiddle -> W1 fp16). Both 256 thr, ~21 KB LDS.
__global__ __launch_bounds__(256) void k1b(const float* __restrict__ x,
                                           const float* __restrict__ rpm,
                                           __half2* __restrict__ w1,
                                           float2* __restrict__ w1c) {
    __shared__ float2 Lw[16 * 137];            // aliased as Ls[128*17] later
    __shared__ float2 chirpT[128];
    __shared__ float2 sWhi[128];
    __shared__ float2 sWlo[128];
    int tid = threadIdx.x;
    int g = tid >> 4, p = tid & 15;
    int bb = p >> 1, r = p & 1;

    load_tabs(sWhi, sWlo, tid);

    if (blockIdx.x < Bn * 8) {
        // ======== bhat pass 1 ========
        int b = blockIdx.x >> 3;
        int t1_0 = (blockIdx.x & 7) << 4;
        int n = compute_n(rpm[b]);
        int two_n = 2 * n;
        float inv_n = 1.0f / (float)n;
        #pragma unroll
        for (int i = 0; i < 8; ++i) {
            int l = i * 256 + tid;
            int t2 = l >> 4, c = l & 15;
            int t = (t1_0 + c) + (t2 << 7);
            int mm = min(t, 16384 - t);
            int ph = (mm * mm) % two_n;
            float sn, cs; __sincosf(PI_F * (float)ph * inv_n, &sn, &cs);
            Lw[c * 137 + IDX(t2)] = make_float2(cs, sn);   // exp(+i b_phase)
        }
        __syncthreads();
        float2 v[8];
        #pragma unroll
        for (int q = 0; q < 8; ++q) v[q] = Lw[g * 137 + IDX(p + 16*q)];
        difR<false>(v, Lw + g * 137, p, sWhi);
        __syncthreads();                        // Lw dead -> alias as Ls
        {
            int t1 = t1_0 + g;
            int k2base = brev7(16*bb + r);
            float2 cur = wtab(sWhi, sWlo, t1 * k2base);
            float2 w8  = wtab(sWhi, sWlo, 8 * t1);
            #pragma unroll
            for (int e = 0; e < 8; ++e) {
                const int s = ((e & 1) << 2) | (e & 2) | ((e & 4) >> 2); // brev3
                Lw[(16*bb + r + 2*s) * 17 + g] = cmul(v[s], cur);
                cur = cmul(cur, w8);
            }
        }
        __syncthreads();
        {
            // w1c[b][j][t1]: per j, 16 float2 = 8 float4 for this t1-group
            float4* wb4 = (float4*)(w1c + ((size_t)b << 14) + t1_0);
            #pragma unroll
            for (int i = 0; i < 4; ++i) {
                int l = i * 256 + tid;          // l < 1024
                int j = l >> 3, w2 = l & 7;
                float2 a0 = Lw[j * 17 + w2*2];
                float2 a1 = Lw[j * 17 + w2*2 + 1];
                wb4[(size_t)j * 64 + w2] = make_float4(a0.x, a0.y, a1.x, a1.y);
            }
        }
        return;
    }

    // ======== main K1 ========
    int bid = blockIdx.x - Bn * 8;
    int b = bid >> 6;
    int t1_0 = (bid & 63) << 1;
    int n = compute_n(rpm[b]);
    int two_n = 2 * n;
    float inv_n = 1.0f / (float)n;
    if (tid < 128) {
        int t2 = tid >> 1, t1l = tid & 1;
        int t = t1_0 + t1l + (t2 << 7);
        int ph = (t * t) % two_n;
        float sn, cs; __sincosf(PI_F * (float)ph * inv_n, &sn, &cs);
        chirpT[tid] = make_float2(cs, -sn);     // exp(-i a_phase)
    }
    __syncthreads();
    {
        // x loads: float4 = 4 ch, 16 B/lane; ONLY t2 < 64 (HZ trim!)
        // 256 elements: t2(64) x t1l(2) x cp(2)
        const float4* xb4 = (const float4*)(x + ((size_t)b << 16));
        int l = tid;                            // l < 256
        int t2 = l >> 2, rem = l & 3;
        int t1l = rem >> 1, cp = rem & 1;
        int t = t1_0 + t1l + (t2 << 7);         // t < 8192
        float4 xv = xb4[(size_t)t * 2 + cp];
        float2 u = chirpT[t2 * 2 + t1l];
        int c = t1l * 8 + cp * 4;
        Lw[c * 137 + IDX(t2)]       = make_float2(xv.x * u.x, xv.x * u.y);
        Lw[(c + 1) * 137 + IDX(t2)] = make_float2(xv.y * u.x, xv.y * u.y);
        Lw[(c + 2) * 137 + IDX(t2)] = make_float2(xv.z * u.x, xv.z * u.y);
        Lw[(c + 3) * 137 + IDX(t2)] = make_float2(xv.w * u.x, xv.w * u.y);
    }
    __syncthreads();
    float2 v[8];
    #pragma unroll
    for (int q = 0; q < 4; ++q) v[q] = Lw[g * 137 + IDX(p + 16*q)];
    difR<true>(v, Lw + g * 137, p, sWhi);
    __syncthreads();                            // Lw dead -> alias as Ls
    {
        int t1 = t1_0 + (g >> 3);
        int k2base = brev7(16*bb + r);
        float2 cur = wtab(sWhi, sWlo, t1 * k2base);
        float2 w8  = wtab(sWhi, sWlo, 8 * t1);
        #pragma unroll
        for (int e = 0; e < 8; ++e) {
            const int s = ((e & 1) << 2) | (e & 2) | ((e & 4) >> 2); // brev3(e)
            Lw[(16*bb + r + 2*s) * 17 + g] = cmul(v[s], cur);
            cur = cmul(cur, w8);
        }
    }
    __syncthreads();
    {
        // W1 writes: float4 = 4 half2, 16 B/lane; per j 64 B contiguous
        float4* wb4 = (float4*)(w1 + ((size_t)b << 17) + (t1_0 << 3));
        #pragma unroll
        for (int i = 0; i < 2; ++i) {
            int l = i * 256 + tid;              // l < 512
            int j = l >> 2, w4 = l & 3;
            float4 val;
            val.x = f2h_bits(Lw[j * 17 + w4*4 + 0]);
            val.y = f2h_bits(Lw[j * 17 + w4*4 + 1]);
            val.z = f2h_bits(Lw[j * 17 + w4*4 + 2]);
            val.w = f2h_bits(Lw[j * 17 + w4*4 + 3]);
            wb4[(size_t)j * 256 + w4] = val;
        }
    }
}

// ---- K2: block=(b, 4-j-slice). W1 -> FFT over t1 -> *Bhat(in-block from
// W1c by wave 0) -> iFFT -> twiddle*(1/M) -> S2 ----
__global__ __launch_bounds__(512) void k2(const __half2* __restrict__ w1,
                                          const float2* __restrict__ w1c,
                                          __half2* __restrict__ s2) {
    __shared__ float2 Lw[32 * 137];            // aliased as Ls[128*33] later
    __shared__ float2 Wsc[4 * 137];            // Bhat scratch+result [s*17+p]
    __shared__ float2 sWhi[128];
    __shared__ float2 sWlo[128];
    int tid = threadIdx.x;
    int g = tid >> 4, p = tid & 15;             // g in [0,32)
    int b = blockIdx.x >> 5;
    int j0 = (blockIdx.x & 31) << 2;

    load_tabs(sWhi, sWlo, tid);
    // Bhat input prefetch (wave 0: groups 0..3 <-> jl 0..3)
    float2 vb[8];
    if (g < 4) {
        const float2* wc = w1c + ((size_t)b << 14) + ((size_t)(j0 + g) << 7);
        #pragma unroll
        for (int q = 0; q < 8; ++q) vb[q] = wc[p + 16*q];
    }
    // stage W1 (fp16): float4 = 4 half2, 16 B/lane, fully coalesced
    {
        const float4* rb4 = (const float4*)(w1 + ((size_t)b << 17) + ((size_t)j0 << 10));
        #pragma unroll
        for (int i = 0; i < 2; ++i) {
            int l = i * 512 + tid;              // l < 1024
            int jl = l >> 8, rem = l & 255, t1 = rem >> 1, ch4 = rem & 1;
            float4 d = rb4[l];
            int c = jl * 8 + ch4 * 4;
            Lw[(c + 0) * 137 + IDX(t1)] = h2f_bits(d.x);
            Lw[(c + 1) * 137 + IDX(t1)] = h2f_bits(d.y);
            Lw[(c + 2) * 137 + IDX(t1)] = h2f_bits(d.z);
            Lw[(c + 3) * 137 + IDX(t1)] = h2f_bits(d.w);
        }
    }
    __syncthreads();
    // wave 0: 4 Bhat row-FFTs into Wsc (result layout [jl][s*17+p], cf-free)
    if (g < 4) {
        difR<false>(vb, Wsc + g * 137, p, sWhi);
        #pragma unroll
        for (int s = 0; s < 8; ++s) Wsc[g * 137 + s * 17 + p] = vb[s];
    }
    // all: main forward FFT over t1
    float2* Lf = Lw + g * 137;
    float2 v[8];
    #pragma unroll
    for (int q = 0; q < 8; ++q) v[q] = Lf[IDX(p + 16*q)];
    difR<false>(v, Lf, p, sWhi);
    __syncthreads();                            // Wsc published
    {
        int jl = g >> 3;
        #pragma unroll
        for (int s = 0; s < 8; ++s) v[s] = cmul(v[s], Wsc[jl * 137 + s * 17 + p]);
    }
    ditR<false>(v, Lf, p, sWhi);
    int j = j0 + (g >> 3);
    int k2v = brev7(j);
    __syncthreads();                            // Lf scratch done -> alias Ls
    {
        float2 cur = wtab(sWhi, sWlo, k2v * p);
        float2 w16 = wtab(sWhi, sWlo, 16 * k2v);
        #pragma unroll
        for (int q = 0; q < 8; ++q) {
            // * exp(+2pi i k2 t1/M) * (1/M)  (scale folded for fp16 range)
            float2 tw = make_float2(cur.x * (1.0f/16384.0f), -cur.y * (1.0f/16384.0f));
            Lw[(p + 16*q) * 33 + g] = cmul(v[q], tw);
            cur = cmul(cur, w16);
        }
    }
    __syncthreads();
    {
        // S2 writes: float4 = 4 half2, 16 B/lane; per t1 128 B contiguous
        float4* sb4 = (float4*)(s2 + ((size_t)b << 17) + (j0 << 3));
        #pragma unroll
        for (int i = 0; i < 2; ++i) {
            int l = i * 512 + tid;              // l < 1024
            int t1 = l >> 3, w4 = l & 7;
            float4 val;
            val.x = f2h_bits(Lw[t1 * 33 + w4*4 + 0]);
            val.y = f2h_bits(Lw[t1 * 33 + w4*4 + 1]);
            val.z = f2h_bits(Lw[t1 * 33 + w4*4 + 2]);
            val.w = f2h_bits(Lw[t1 * 33 + w4*4 + 3]);
            sb4[(size_t)t1 * 256 + w4] = val;
        }
    }
}

// ---- K3: block=(b, t1-pair). S2 -> iFFT over j -> |.| -> out ----
__global__ __launch_bounds__(256) void k3(const __half2* __restrict__ s2,
                                          float* __restrict__ outF) {
    __shared__ float2 Lw[16 * 137];            // aliased as float Lsf later
    __shared__ float2 sWhi[128];
    __shared__ float2 sWlo[128];
    int tid = threadIdx.x;
    int g = tid >> 4, p = tid & 15;
    int bb = p >> 1, r = p & 1;
    int b = blockIdx.x >> 6;
    int t1_0 = (blockIdx.x & 63) << 1;

    load_tabs(sWhi, sWlo, tid);
    {
        // S2 reads: float4 = 4 half2, 16 B/lane, fully coalesced
        const float4* rb4 = (const float4*)(s2 + ((size_t)b << 17) + ((size_t)t1_0 << 10));
        #pragma unroll
        for (int i = 0; i < 2; ++i) {
            int l = i * 256 + tid;              // l < 512
            int t1l = l >> 8, rem = l & 255, j = rem >> 1, ch4 = rem & 1;
            float4 d = rb4[l];
            int c = t1l * 8 + ch4 * 4;
            Lw[(c + 0) * 137 + IDX(j)] = h2f_bits(d.x);
            Lw[(c + 1) * 137 + IDX(j)] = h2f_bits(d.y);
            Lw[(c + 2) * 137 + IDX(j)] = h2f_bits(d.z);
            Lw[(c + 3) * 137 + IDX(j)] = h2f_bits(d.w);
        }
    }
    __syncthreads();
    float2 v[8];
    {
        float2* Lf = Lw + g * 137;
        #pragma unroll
        for (int s = 0; s < 8; ++s) v[s] = Lf[IDX(16*bb + r + 2*s)];
        ditR<true>(v, Lf, p, sWhi);
    }
    __syncthreads();                            // Lw dead -> alias float Lsf
    float* Lsf = (float*)Lw;
    #pragma unroll
    for (int q = 0; q < 4; ++q) {
        // v[q] = z[m = t1 + 128*(p+16q)], q<4 (1/M applied in k2)
        float2 z = v[q];
        Lsf[(p + 16*q) * 20 + g] = sqrtf(z.x*z.x + z.y*z.y);
    }
    __syncthreads();
    {
        // out writes: float4 = 4 ch, 16 B/lane; 64 B line-complete per (m)
        float4* ob4 = (float4*)(outF + ((size_t)b << 16) + (t1_0 << 3));
        int t2 = tid >> 2, t1l = (tid >> 1) & 1, ch4 = tid & 1;
        int base = t2 * 20 + t1l * 8 + ch4 * 4;
        float4 val = make_float4(Lsf[base], Lsf[base + 1], Lsf[base + 2], Lsf[base + 3]);
        ob4[t2 * 256 + t1l * 2 + ch4] = val;
    }
}

// ---------------- launch ----------------
extern "C" void kernel_launch(void* const* d_in, const int* in_sizes, int n_in,
                              void* d_out, int out_size, void* d_ws, size_t ws_size,
                              hipStream_t stream) {
    const float* x   = (const float*)d_in[0];
    const float* rpm = (const float*)d_in[1];
    float* outF = (float*)d_out;
    __half2* w1  = (__half2*)d_ws;                               // 32 MiB
    __half2* s2  = w1 + (size_t)Bn * 131072;                     // 32 MiB
    float2* w1c  = (float2*)(s2 + (size_t)Bn * 131072);          // 8 MiB

    k1b<<<Bn * 8 + Bn * 64, 256, 0, stream>>>(x, rpm, w1, w1c);
    k2<<<Bn * 32, 512, 0, stream>>>(w1, w1c, s2);
    k3<<<Bn * 64, 256, 0, stream>>>(s2, outF);
}